// Round 4
// baseline (1767.222 us; speedup 1.0000x reference)
//
#include <hip/hip_runtime.h>
#include <hip/hip_cooperative_groups.h>
#include <math.h>

namespace cg = cooperative_groups;

constexpr int cB = 8, cT = 2048, cDU = 512, cDM = 512, cDA = 256, cDF = 12, cL = 4;
constexpr float cEPS = 1e-6f;
constexpr float cSCALE = 16.0f;   // sqrt(DA)
constexpr float cGAMMA = 1.0f;

typedef unsigned short u16;
typedef u16 u16x8 __attribute__((ext_vector_type(8)));

// ---------------- workspace layout ----------------
constexpr size_t F_SB = 0;                 // sbias  B*T
constexpr size_t F_UN = F_SB + 16384;      // unorm2 B*T
constexpr size_t F_LG = F_UN + 16384;      // logits B*T
constexpr size_t F_Y  = F_LG + 16384;      // y      B*T
constexpr size_t F_PR = F_Y  + 16384;      // prev   B*T
constexpr size_t F_OV = F_PR + 16384;      // overlap B*T
constexpr size_t F_SP = F_OV + 16384;      // spread partials B*64
constexpr size_t F_QK = F_SP + 2048;       // qk  B*DU
constexpr size_t F_M0 = F_QK + 4096;       // memory buf 0
constexpr size_t F_M1 = F_M0 + 4096;       // memory buf 1
constexpr size_t F_C  = F_M1 + 4096;       // c_raw B*DU
constexpr size_t F_CN = F_C  + 4096;       // cnorm B*DU
constexpr size_t F_Z  = F_CN + 4096;       // z B*DU
constexpr size_t F_SC = F_Z  + 4096;       // scalars B*8
constexpr size_t F_END = F_SC + 64;
constexpr size_t U_OFFB   = F_END * 4;
constexpr size_t U_BYTES  = (size_t)cB * cT * cDU * 2;
constexpr size_t SIM_OFFB = U_OFFB + U_BYTES;
constexpr size_t SIM_BYTES= (size_t)cB * cT * cT * 2;
constexpr size_t WS_NEED_U   = U_OFFB + U_BYTES;
constexpr size_t WS_NEED_ALL = SIM_OFFB + SIM_BYTES;
// scal: 0 ysum_clamped, 1 coverage, 2 entropy, 3 wsq, 6 csq, 7 cen2

__device__ __forceinline__ float wave_sum(float v) {
#pragma unroll
  for (int o = 32; o; o >>= 1) v += __shfl_down(v, o);
  return v;   // valid on lane 0
}
__device__ __forceinline__ u16 f2bf(float f) {
  unsigned u = __float_as_uint(f);
  unsigned r = (u + 0x7fffu + ((u >> 16) & 1u)) >> 16;
  return (u16)r;
}
__device__ __forceinline__ float bf2f(u16 h) { return __uint_as_float(((unsigned)h) << 16); }
__device__ __forceinline__ float dot4(float4 a, float4 b) {
  return a.x * b.x + a.y * b.y + a.z * b.z + a.w * b.w;
}

// =================== persistent cooperative mega-kernel ===================
__global__ __launch_bounds__(256) void mega(
    const float* __restrict__ u, const float* __restrict__ sf,
    const float* __restrict__ sim, const float* __restrict__ mem0,
    const float* __restrict__ Wq, const float* __restrict__ Wk,
    const float* __restrict__ Wv,
    const float* __restrict__ sbw1, const float* __restrict__ sbb1,
    const float* __restrict__ sbw2, const float* __restrict__ sbb2,
    const float* __restrict__ logt,
    const float* __restrict__ W_ih, const float* __restrict__ b_ih,
    const float* __restrict__ W_hh, const float* __restrict__ b_hh,
    float* __restrict__ out, float* __restrict__ wsf,
    u16* __restrict__ ubf, u16* __restrict__ simbf,
    int use_ubf, int use_simbf) {
  cg::grid_group grid = cg::this_grid();
  __shared__ float lds[2048];
  const int tid = threadIdx.x;
  const int wv = tid >> 6, lane = tid & 63;
  const int nb = gridDim.x;
  const int gw = blockIdx.x * 4 + wv;
  const int nw = nb * 4;
  const int gt = blockIdx.x * 256 + tid;
  const int nt = nb * 256;

  float* sbias = wsf + F_SB;  float* unorm2 = wsf + F_UN;
  float* logits = wsf + F_LG; float* y = wsf + F_Y;
  float* prev = wsf + F_PR;   float* overlap = wsf + F_OV;
  float* sprp = wsf + F_SP;   float* qk = wsf + F_QK;
  float* c_raw = wsf + F_C;   float* cnorm = wsf + F_CN;
  float* z = wsf + F_Z;       float* scal = wsf + F_SC;

  // ---------- P0: memory init + bf16 casts + sbias/unorm2 ----------
  for (int i = gt; i < cB * cDM; i += nt) wsf[F_M0 + i] = mem0[i];
  if (use_ubf) {
    const int NU8 = cB * cT * cDU / 8;
    const float4* src = (const float4*)u;
    for (int c = gt; c < NU8; c += nt) {
      float4 f0 = src[(size_t)c * 2], f1 = src[(size_t)c * 2 + 1];
      u16x8 o;
      o[0] = f2bf(f0.x); o[1] = f2bf(f0.y); o[2] = f2bf(f0.z); o[3] = f2bf(f0.w);
      o[4] = f2bf(f1.x); o[5] = f2bf(f1.y); o[6] = f2bf(f1.z); o[7] = f2bf(f1.w);
      *(u16x8*)(ubf + (size_t)c * 8) = o;
    }
  }
  if (use_simbf) {
    const int NS8 = cB * cT * cT / 8;
    const float4* src = (const float4*)sim;
    for (int c = gt; c < NS8; c += nt) {
      float4 f0 = src[(size_t)c * 2], f1 = src[(size_t)c * 2 + 1];
      u16x8 o;
      o[0] = f2bf(f0.x); o[1] = f2bf(f0.y); o[2] = f2bf(f0.z); o[3] = f2bf(f0.w);
      o[4] = f2bf(f1.x); o[5] = f2bf(f1.y); o[6] = f2bf(f1.z); o[7] = f2bf(f1.w);
      *(u16x8*)(simbf + (size_t)c * 8) = o;
    }
  }
  for (int row = gw; row < cB * cT; row += nw) {
    float d0 = sf[(size_t)row * cDF + 8];
    float d1 = sf[(size_t)row * cDF + 9];
    float d2 = sf[(size_t)row * cDF + 10];
    float acc = 0.f;
#pragma unroll
    for (int i = 0; i < 4; ++i) {
      int a = lane * 4 + i;
      float h = d0 * sbw1[a * 3 + 0] + d1 * sbw1[a * 3 + 1] + d2 * sbw1[a * 3 + 2] + sbb1[a];
      float g = 0.5f * h * (1.0f + erff(h * 0.70710678118654752f));
      acc += g * sbw2[a];
    }
    float un = 0.f;
    const float4* ur = (const float4*)(u + (size_t)row * cDU);
#pragma unroll
    for (int m = 0; m < 2; ++m) { float4 x = ur[lane + m * 64]; un += dot4(x, x); }
    acc = wave_sum(acc);
    un = wave_sum(un);
    if (lane == 0) { sbias[row] = acc + sbb2[0]; unorm2[row] = un; }
  }
  grid.sync();

  // ---------- stage loop ----------
  for (int st = 0; st < cL; ++st) {
    const float* memin = wsf + ((st & 1) ? F_M1 : F_M0);
    float* memout = wsf + ((st & 1) ? F_M0 : F_M1);

    // --- A: q = mem@Wq^T ; qk = Wk^T@q  (blocks 0..7) ---
    if (blockIdx.x < cB) {
      int b = blockIdx.x;
      const float4* mr = (const float4*)(memin + (size_t)b * cDM);
      float4 m0 = mr[lane * 2], m1 = mr[lane * 2 + 1];
      for (int ii = 0; ii < 64; ++ii) {
        int a = wv * 64 + ii;
        const float4* wr = (const float4*)(Wq + (size_t)a * cDM);
        float acc = dot4(m0, wr[lane * 2]) + dot4(m1, wr[lane * 2 + 1]);
        acc = wave_sum(acc);
        if (lane == 0) lds[a] = acc;
      }
      __syncthreads();
      float acc0 = 0.f, acc1 = 0.f;
      for (int a = 0; a < cDA; ++a) {
        float qa = lds[a];
        acc0 += Wk[(size_t)a * cDU + tid] * qa;
        acc1 += Wk[(size_t)a * cDU + tid + 256] * qa;
      }
      qk[b * cDU + tid] = acc0;
      qk[b * cDU + tid + 256] = acc1;
    }
    grid.sync();

    // --- B: logits = (u.qk/SCALE + sbias - gamma*sim@prev)/temp ---
    {
      float tmp = fminf(fmaxf(expf(logt[0]), 0.1f), 10.0f);
      float gamma = (st == 0) ? 0.0f : cGAMMA;
      for (int row = gw; row < cB * cT; row += nw) {
        int b = row >> 11;
        const float4* qk4 = (const float4*)(qk + (size_t)b * cDU);
        float4 q0 = qk4[lane * 2], q1 = qk4[lane * 2 + 1];
        float acc;
        if (use_ubf) {
          u16x8 s8 = *(const u16x8*)(ubf + (size_t)row * cDU + lane * 8);
          acc = bf2f(s8[0]) * q0.x + bf2f(s8[1]) * q0.y + bf2f(s8[2]) * q0.z + bf2f(s8[3]) * q0.w +
                bf2f(s8[4]) * q1.x + bf2f(s8[5]) * q1.y + bf2f(s8[6]) * q1.z + bf2f(s8[7]) * q1.w;
        } else {
          const float4* ur = (const float4*)(u + (size_t)row * cDU);
          acc = dot4(ur[lane * 2], q0) + dot4(ur[lane * 2 + 1], q1);
        }
        acc *= (1.0f / cSCALE);
        if (gamma != 0.0f) {
          float sd = 0.f;
          const float4* pr4 = (const float4*)(prev + (size_t)b * cT);
          if (use_simbf) {
#pragma unroll
            for (int m = 0; m < 4; ++m) {
              u16x8 s8 = *(const u16x8*)(simbf + (size_t)row * cT + m * 512 + lane * 8);
              float4 p0 = pr4[m * 128 + lane * 2], p1 = pr4[m * 128 + lane * 2 + 1];
              sd += bf2f(s8[0]) * p0.x + bf2f(s8[1]) * p0.y + bf2f(s8[2]) * p0.z + bf2f(s8[3]) * p0.w +
                    bf2f(s8[4]) * p1.x + bf2f(s8[5]) * p1.y + bf2f(s8[6]) * p1.z + bf2f(s8[7]) * p1.w;
            }
          } else {
            const float4* sr = (const float4*)(sim + (size_t)row * cT);
#pragma unroll
            for (int m = 0; m < 8; ++m) sd += dot4(sr[lane + m * 64], pr4[lane + m * 64]);
          }
          acc -= gamma * sd;
        }
        acc = wave_sum(acc);
        if (lane == 0) logits[row] = (acc + sbias[row]) * (1.0f / tmp);
      }
    }
    grid.sync();

    // --- C: softmax over T per b (blocks 0..7) ---
    if (blockIdx.x < cB) {
      int b = blockIdx.x;
      float l[8];
      float mx = -INFINITY;
#pragma unroll
      for (int e = 0; e < 8; ++e) { l[e] = logits[b * cT + e * 256 + tid]; mx = fmaxf(mx, l[e]); }
      lds[tid] = mx; __syncthreads();
      for (int s2 = 128; s2; s2 >>= 1) { if (tid < s2) lds[tid] = fmaxf(lds[tid], lds[tid + s2]); __syncthreads(); }
      mx = lds[0]; __syncthreads();
      float sum = 0.f;
#pragma unroll
      for (int e = 0; e < 8; ++e) { l[e] = expf(l[e] - mx); sum += l[e]; }
      lds[tid] = sum; __syncthreads();
      for (int s2 = 128; s2; s2 >>= 1) { if (tid < s2) lds[tid] += lds[tid + s2]; __syncthreads(); }
      float inv = 1.f / lds[0]; __syncthreads();
#pragma unroll
      for (int e = 0; e < 8; ++e) y[b * cT + e * 256 + tid] = l[e] * inv;
    }
    grid.sync();

    // --- D: overlap = sim @ y ---
    for (int row = gw; row < cB * cT; row += nw) {
      int b = row >> 11;
      const float4* yr4 = (const float4*)(y + (size_t)b * cT);
      float acc = 0.f;
      if (use_simbf) {
#pragma unroll
        for (int m = 0; m < 4; ++m) {
          u16x8 s8 = *(const u16x8*)(simbf + (size_t)row * cT + m * 512 + lane * 8);
          float4 p0 = yr4[m * 128 + lane * 2], p1 = yr4[m * 128 + lane * 2 + 1];
          acc += bf2f(s8[0]) * p0.x + bf2f(s8[1]) * p0.y + bf2f(s8[2]) * p0.z + bf2f(s8[3]) * p0.w +
                 bf2f(s8[4]) * p1.x + bf2f(s8[5]) * p1.y + bf2f(s8[6]) * p1.z + bf2f(s8[7]) * p1.w;
        }
      } else {
        const float4* sr = (const float4*)(sim + (size_t)row * cT);
#pragma unroll
        for (int m = 0; m < 8; ++m) acc += dot4(sr[lane + m * 64], yr4[lane + m * 64]);
      }
      acc = wave_sum(acc);
      if (lane == 0) overlap[row] = acc;
    }
    grid.sync();

    // --- E: penalty + resoftmax + prev + stats + zero c_raw (blocks 0..7) ---
    if (blockIdx.x < cB) {
      int b = blockIdx.x;
      float o[8], l[8], yv[8];
      float mo = -INFINITY;
#pragma unroll
      for (int e = 0; e < 8; ++e) { o[e] = overlap[b * cT + e * 256 + tid]; mo = fmaxf(mo, o[e]); }
      lds[tid] = mo; __syncthreads();
      for (int s2 = 128; s2; s2 >>= 1) { if (tid < s2) lds[tid] = fmaxf(lds[tid], lds[tid + s2]); __syncthreads(); }
      mo = fmaxf(lds[0], cEPS); __syncthreads();
      float ml = -INFINITY;
#pragma unroll
      for (int e = 0; e < 8; ++e) { l[e] = logits[b * cT + e * 256 + tid] - o[e] / mo; ml = fmaxf(ml, l[e]); }
      lds[tid] = ml; __syncthreads();
      for (int s2 = 128; s2; s2 >>= 1) { if (tid < s2) lds[tid] = fmaxf(lds[tid], lds[tid + s2]); __syncthreads(); }
      ml = lds[0]; __syncthreads();
      float sum = 0.f;
#pragma unroll
      for (int e = 0; e < 8; ++e) { l[e] = expf(l[e] - ml); sum += l[e]; }
      lds[tid] = sum; __syncthreads();
      for (int s2 = 128; s2; s2 >>= 1) { if (tid < s2) lds[tid] += lds[tid + s2]; __syncthreads(); }
      float inv = 1.f / lds[0]; __syncthreads();
      float ysr_p = 0.f, wsq_p = 0.f;
#pragma unroll
      for (int e = 0; e < 8; ++e) {
        int idx = b * cT + e * 256 + tid;
        yv[e] = l[e] * inv;
        y[idx] = yv[e];
        if (st == 0) prev[idx] = yv[e]; else prev[idx] += yv[e];
        ysr_p += yv[e];
        wsq_p += yv[e] * unorm2[idx];
      }
      lds[tid] = ysr_p; __syncthreads();
      for (int s2 = 128; s2; s2 >>= 1) { if (tid < s2) lds[tid] += lds[tid + s2]; __syncthreads(); }
      float ysr = lds[0]; __syncthreads();
      float ysc = fmaxf(ysr, cEPS);
      lds[tid] = wsq_p; __syncthreads();
      for (int s2 = 128; s2; s2 >>= 1) { if (tid < s2) lds[tid] += lds[tid + s2]; __syncthreads(); }
      float wsq = lds[0]; __syncthreads();
      float ent_p = 0.f;
#pragma unroll
      for (int e = 0; e < 8; ++e) {
        float yn = yv[e] / ysc;
        ent_p -= yn * logf(fmaxf(yn, cEPS));
      }
      lds[tid] = ent_p; __syncthreads();
      for (int s2 = 128; s2; s2 >>= 1) { if (tid < s2) lds[tid] += lds[tid + s2]; __syncthreads(); }
      float ent = lds[0]; __syncthreads();
      c_raw[b * cDU + tid] = 0.f;
      c_raw[b * cDU + tid + 256] = 0.f;
      if (tid == 0) {
        scal[b * 8 + 0] = ysc;
        scal[b * 8 + 1] = ysr / (float)cT;
        scal[b * 8 + 2] = ent;
        scal[b * 8 + 3] = wsq;
      }
    }
    grid.sync();

    // --- F: c_raw += y @ u (512 units of 32 rows) ---
    for (int unit = blockIdx.x; unit < 512; unit += nb) {
      int b = unit >> 6, ch = unit & 63;
      float acc[8] = {};
      for (int i = 0; i < 8; ++i) {
        int row = b * cT + ch * 32 + wv * 8 + i;
        float yvv = y[row];
        if (use_ubf) {
          u16x8 s8 = *(const u16x8*)(ubf + (size_t)row * cDU + lane * 8);
#pragma unroll
          for (int e = 0; e < 8; ++e) acc[e] += yvv * bf2f(s8[e]);
        } else {
          const float4* ur = (const float4*)(u + (size_t)row * cDU);
          float4 a0 = ur[lane * 2], a1 = ur[lane * 2 + 1];
          acc[0] += yvv * a0.x; acc[1] += yvv * a0.y; acc[2] += yvv * a0.z; acc[3] += yvv * a0.w;
          acc[4] += yvv * a1.x; acc[5] += yvv * a1.y; acc[6] += yvv * a1.z; acc[7] += yvv * a1.w;
        }
      }
      __syncthreads();
#pragma unroll
      for (int e = 0; e < 8; ++e) lds[wv * 512 + lane * 8 + e] = acc[e];
      __syncthreads();
      float s0 = lds[tid] + lds[512 + tid] + lds[1024 + tid] + lds[1536 + tid];
      float s1 = lds[tid + 256] + lds[512 + tid + 256] + lds[1024 + tid + 256] + lds[1536 + tid + 256];
      atomicAdd(&c_raw[b * cDU + tid], s0);
      atomicAdd(&c_raw[b * cDU + tid + 256], s1);
    }
    grid.sync();

    // --- G: cnorm finalize (blocks 0..7) ; z = c_raw@Wv^T (blocks 8+) ---
    if (blockIdx.x < cB) {
      int b = blockIdx.x;
      float ysc = scal[b * 8 + 0];
      float c0 = c_raw[b * cDU + tid], c1 = c_raw[b * cDU + tid + 256];
      float n0 = c0 / ysc, n1 = c1 / ysc;
      cnorm[b * cDU + tid] = n0; cnorm[b * cDU + tid + 256] = n1;
      lds[tid] = c0 * c0 + c1 * c1; __syncthreads();
      for (int s2 = 128; s2; s2 >>= 1) { if (tid < s2) lds[tid] += lds[tid + s2]; __syncthreads(); }
      float csq = lds[0]; __syncthreads();
      lds[tid] = n0 * n0 + n1 * n1; __syncthreads();
      for (int s2 = 128; s2; s2 >>= 1) { if (tid < s2) lds[tid] += lds[tid + s2]; __syncthreads(); }
      if (tid == 0) { scal[b * 8 + 6] = csq; scal[b * 8 + 7] = lds[0]; }
    } else {
      int zw = (blockIdx.x - cB) * 4 + wv;
      int nzw = (nb - cB) * 4;
      for (int idx = zw; idx < cB * cDU; idx += nzw) {
        int b = idx >> 9, j = idx & 511;
        const float4* c4 = (const float4*)(c_raw + (size_t)b * cDU);
        const float4* w4 = (const float4*)(Wv + (size_t)j * cDU);
        float acc = dot4(c4[lane * 2], w4[lane * 2]) + dot4(c4[lane * 2 + 1], w4[lane * 2 + 1]);
        acc = wave_sum(acc);
        if (lane == 0) z[idx] = acc;
      }
    }
    grid.sync();

    // --- H: spread partials sprp[b*64+ch] ---
    for (int unit = blockIdx.x; unit < 512; unit += nb) {
      int b = unit >> 6, ch = unit & 63;
      const float4* cr = (const float4*)(cnorm + (size_t)b * cDU);
      float4 cx0 = cr[lane * 2], cx1 = cr[lane * 2 + 1];
      float cen2 = scal[b * 8 + 7];
      float part = 0.f;
      for (int i = 0; i < 8; ++i) {
        int row = b * cT + ch * 32 + wv * 8 + i;
        float dot;
        if (use_ubf) {
          u16x8 s8 = *(const u16x8*)(ubf + (size_t)row * cDU + lane * 8);
          dot = bf2f(s8[0]) * cx0.x + bf2f(s8[1]) * cx0.y + bf2f(s8[2]) * cx0.z + bf2f(s8[3]) * cx0.w +
                bf2f(s8[4]) * cx1.x + bf2f(s8[5]) * cx1.y + bf2f(s8[6]) * cx1.z + bf2f(s8[7]) * cx1.w;
        } else {
          const float4* ur = (const float4*)(u + (size_t)row * cDU);
          dot = dot4(ur[lane * 2], cx0) + dot4(ur[lane * 2 + 1], cx1);
        }
        dot = wave_sum(dot);
        if (lane == 0) {
          float d2 = unorm2[row] - 2.f * dot + cen2;
          part += y[row] * sqrtf(fmaxf(d2, 0.f));
        }
      }
      __syncthreads();
      if (lane == 0) lds[wv] = part;
      __syncthreads();
      if (tid == 0) sprp[unit] = lds[0] + lds[1] + lds[2] + lds[3];
    }
    grid.sync();

    // --- I: fused GRU + output ---
    for (int idx = gw; idx < cB * cDM; idx += nw) {
      int b = idx >> 9, i = idx & 511;
      const float4* xz = (const float4*)(z + (size_t)b * cDU);
      const float4* xm = (const float4*)(memin + (size_t)b * cDM);
      float4 z0 = xz[lane * 2], z1 = xz[lane * 2 + 1];
      float4 m0 = xm[lane * 2], m1 = xm[lane * 2 + 1];
      float ysc = scal[b * 8 + 0];
      float spr_raw = wave_sum(sprp[b * 64 + lane]);   // lane0-valid
      float aI[3], aH[3];
#pragma unroll
      for (int g = 0; g < 3; ++g) {
        size_t row = (size_t)(g * 512 + i);
        const float4* wI = (const float4*)(W_ih + row * 516);
        float a = dot4(z0, wI[lane * 2]) + dot4(z1, wI[lane * 2 + 1]);
        if (lane == 0) {
          float4 wt = wI[128];
          float cov = scal[b * 8 + 1], ent = scal[b * 8 + 2];
          float spr = spr_raw / ysc;
          float cmp = 2.f * (ysc * scal[b * 8 + 3] - scal[b * 8 + 6]) / fmaxf(ysc * ysc, cEPS);
          a += cov * wt.x + ent * wt.y + spr * wt.z + cmp * wt.w;
        }
        aI[g] = wave_sum(a);
        const float4* wH = (const float4*)(W_hh + row * cDM);
        float h = dot4(m0, wH[lane * 2]) + dot4(m1, wH[lane * 2 + 1]);
        aH[g] = wave_sum(h);
      }
      if (lane == 0) {
        float gir = aI[0] + b_ih[i],        ghr = aH[0] + b_hh[i];
        float giz = aI[1] + b_ih[512 + i],  ghz = aH[1] + b_hh[512 + i];
        float gin = aI[2] + b_ih[1024 + i], ghn = aH[2] + b_hh[1024 + i];
        float rg = 1.f / (1.f + expf(-(gir + ghr)));
        float zg = 1.f / (1.f + expf(-(giz + ghz)));
        float ng = tanhf(gin + rg * ghn);
        float mold = memin[b * cDM + i];
        memout[b * cDM + i] = (1.f - zg) * ng + zg * mold;
        out[(size_t)(b * cL + st) * cDU + i] = z[b * cDU + i];
      }
    }
    grid.sync();
  }
}

// =================== fallback multi-kernel path (round-3, proven) ===================
__device__ __forceinline__ float block_reduce_sum(float v, float* red) {
  int tid = threadIdx.x;
  red[tid] = v; __syncthreads();
  for (int s = 512; s; s >>= 1) { if (tid < s) red[tid] += red[tid + s]; __syncthreads(); }
  float r = red[0]; __syncthreads();
  return r;
}
__device__ __forceinline__ float block_reduce_max(float v, float* red) {
  int tid = threadIdx.x;
  red[tid] = v; __syncthreads();
  for (int s = 512; s; s >>= 1) { if (tid < s) red[tid] = fmaxf(red[tid], red[tid + s]); __syncthreads(); }
  float r = red[0]; __syncthreads();
  return r;
}

__global__ void k_cast(const float* __restrict__ u, const float* __restrict__ sim,
                       u16* __restrict__ ubf, u16* __restrict__ simbf, int do_sim) {
  const int NU8 = (cB * cT * cDU) / 8;
  const int NS8 = (cB * cT * cT) / 8;
  int total = do_sim ? (NU8 + NS8) : NU8;
  for (int idx = blockIdx.x * blockDim.x + threadIdx.x; idx < total;
       idx += gridDim.x * blockDim.x) {
    const float4* src; u16* dst; size_t c;
    if (idx < NU8) { src = (const float4*)u; dst = ubf; c = idx; }
    else           { src = (const float4*)sim; dst = simbf; c = idx - NU8; }
    float4 f0 = src[c * 2], f1 = src[c * 2 + 1];
    u16x8 o;
    o[0] = f2bf(f0.x); o[1] = f2bf(f0.y); o[2] = f2bf(f0.z); o[3] = f2bf(f0.w);
    o[4] = f2bf(f1.x); o[5] = f2bf(f1.y); o[6] = f2bf(f1.z); o[7] = f2bf(f1.w);
    *(u16x8*)(dst + c * 8) = o;
  }
}

__global__ void k_pre(const float* __restrict__ sf, const float* __restrict__ u,
                      const float* __restrict__ w1, const float* __restrict__ b1,
                      const float* __restrict__ w2, const float* __restrict__ b2,
                      float* __restrict__ sbias, float* __restrict__ unorm2) {
  int wid = (blockIdx.x * blockDim.x + threadIdx.x) >> 6;
  int lane = threadIdx.x & 63;
  float d0 = sf[(size_t)wid * cDF + 8];
  float d1 = sf[(size_t)wid * cDF + 9];
  float d2 = sf[(size_t)wid * cDF + 10];
  float acc = 0.f;
#pragma unroll
  for (int i = 0; i < 4; ++i) {
    int a = lane * 4 + i;
    float h = d0 * w1[a * 3 + 0] + d1 * w1[a * 3 + 1] + d2 * w1[a * 3 + 2] + b1[a];
    float g = 0.5f * h * (1.0f + erff(h * 0.70710678118654752f));
    acc += g * w2[a];
  }
  float un = 0.f;
  const float4* ur = (const float4*)(u + (size_t)wid * cDU);
#pragma unroll
  for (int m = 0; m < 2; ++m) { float4 x = ur[lane + m * 64]; un += dot4(x, x); }
  acc = wave_sum(acc);
  un = wave_sum(un);
  if (lane == 0) { sbias[wid] = acc + b2[0]; unorm2[wid] = un; }
}

__global__ __launch_bounds__(1024) void k_qqk(const float* __restrict__ mem,
                                              const float* __restrict__ Wq,
                                              const float* __restrict__ Wk,
                                              float* __restrict__ qk) {
  __shared__ float qs[cDA];
  __shared__ float red2[1024];
  int b = blockIdx.x, tid = threadIdx.x;
  int wv = tid >> 6, lane = tid & 63;
  const float4* mr = (const float4*)(mem + (size_t)b * cDM);
  float4 m0 = mr[lane * 2], m1 = mr[lane * 2 + 1];
#pragma unroll
  for (int ii = 0; ii < 16; ++ii) {
    int a = wv * 16 + ii;
    const float4* wr = (const float4*)(Wq + (size_t)a * cDM);
    float acc = dot4(m0, wr[lane * 2]) + dot4(m1, wr[lane * 2 + 1]);
    acc = wave_sum(acc);
    if (lane == 0) qs[a] = acc;
  }
  __syncthreads();
  int j = tid & 511;
  int half = tid >> 9;
  float acc = 0.f;
#pragma unroll 4
  for (int a = half * 128; a < half * 128 + 128; ++a)
    acc += Wk[(size_t)a * cDU + j] * qs[a];
  red2[tid] = acc;
  __syncthreads();
  if (tid < 512) qk[b * cDU + j] = red2[tid] + red2[tid + 512];
}

__global__ void k_scores(const u16* __restrict__ ubf, const float* __restrict__ uf,
                         const float* __restrict__ qk, const float* __restrict__ sbias,
                         const u16* __restrict__ simbf, const float* __restrict__ simf,
                         const float* __restrict__ prev, const float* __restrict__ log_temp,
                         float gamma, int use_ubf, int use_simbf,
                         float* __restrict__ logits) {
  int wid = (blockIdx.x * blockDim.x + threadIdx.x) >> 6;
  int lane = threadIdx.x & 63;
  int b = wid >> 11;
  const float4* qk4 = (const float4*)(qk + (size_t)b * cDU);
  float4 q0 = qk4[lane * 2], q1 = qk4[lane * 2 + 1];
  float acc;
  if (use_ubf) {
    u16x8 s = *(const u16x8*)(ubf + (size_t)wid * cDU + lane * 8);
    acc = bf2f(s[0]) * q0.x + bf2f(s[1]) * q0.y + bf2f(s[2]) * q0.z + bf2f(s[3]) * q0.w +
          bf2f(s[4]) * q1.x + bf2f(s[5]) * q1.y + bf2f(s[6]) * q1.z + bf2f(s[7]) * q1.w;
  } else {
    const float4* ur = (const float4*)(uf + (size_t)wid * cDU);
    acc = dot4(ur[lane * 2], q0) + dot4(ur[lane * 2 + 1], q1);
  }
  acc *= (1.0f / cSCALE);
  if (gamma != 0.0f) {
    float sd = 0.f;
    const float4* pr4 = (const float4*)(prev + (size_t)b * cT);
    if (use_simbf) {
#pragma unroll
      for (int m = 0; m < 4; ++m) {
        u16x8 s = *(const u16x8*)(simbf + (size_t)wid * cT + m * 512 + lane * 8);
        float4 p0 = pr4[m * 128 + lane * 2], p1 = pr4[m * 128 + lane * 2 + 1];
        sd += bf2f(s[0]) * p0.x + bf2f(s[1]) * p0.y + bf2f(s[2]) * p0.z + bf2f(s[3]) * p0.w +
              bf2f(s[4]) * p1.x + bf2f(s[5]) * p1.y + bf2f(s[6]) * p1.z + bf2f(s[7]) * p1.w;
      }
    } else {
      const float4* sr = (const float4*)(simf + (size_t)wid * cT);
#pragma unroll
      for (int m = 0; m < 8; ++m) sd += dot4(sr[lane + m * 64], pr4[lane + m * 64]);
    }
    acc -= gamma * sd;
  }
  acc = wave_sum(acc);
  if (lane == 0) {
    float temp = fminf(fmaxf(expf(log_temp[0]), 0.1f), 10.0f);
    logits[wid] = (acc + sbias[wid]) / temp;
  }
}

__global__ __launch_bounds__(1024) void k_softmax(const float* __restrict__ logits,
                                                  float* __restrict__ y) {
  __shared__ float red[1024];
  int b = blockIdx.x, tid = threadIdx.x;
  int i0 = b * cT + tid, i1 = i0 + 1024;
  float l0 = logits[i0], l1 = logits[i1];
  float m = block_reduce_max(fmaxf(l0, l1), red);
  float e0 = expf(l0 - m), e1 = expf(l1 - m);
  float S = block_reduce_sum(e0 + e1, red);
  y[i0] = e0 / S; y[i1] = e1 / S;
}

__global__ void k_overlap(const u16* __restrict__ simbf, const float* __restrict__ simf,
                          const float* __restrict__ y, int use_simbf,
                          float* __restrict__ overlap) {
  int wid = (blockIdx.x * blockDim.x + threadIdx.x) >> 6;
  int lane = threadIdx.x & 63;
  int b = wid >> 11;
  const float4* yr4 = (const float4*)(y + (size_t)b * cT);
  float acc = 0.f;
  if (use_simbf) {
#pragma unroll
    for (int m = 0; m < 4; ++m) {
      u16x8 s = *(const u16x8*)(simbf + (size_t)wid * cT + m * 512 + lane * 8);
      float4 p0 = yr4[m * 128 + lane * 2], p1 = yr4[m * 128 + lane * 2 + 1];
      acc += bf2f(s[0]) * p0.x + bf2f(s[1]) * p0.y + bf2f(s[2]) * p0.z + bf2f(s[3]) * p0.w +
             bf2f(s[4]) * p1.x + bf2f(s[5]) * p1.y + bf2f(s[6]) * p1.z + bf2f(s[7]) * p1.w;
    }
  } else {
    const float4* sr = (const float4*)(simf + (size_t)wid * cT);
#pragma unroll
    for (int m = 0; m < 8; ++m) acc += dot4(sr[lane + m * 64], yr4[lane + m * 64]);
  }
  acc = wave_sum(acc);
  if (lane == 0) overlap[wid] = acc;
}

__global__ __launch_bounds__(1024) void k_soft2(const float* __restrict__ overlap,
                                                const float* __restrict__ logits,
                                                float* __restrict__ y, float* __restrict__ prev,
                                                const float* __restrict__ unorm2,
                                                float* __restrict__ scal,
                                                float* __restrict__ c_raw, int first_stage) {
  __shared__ float red[1024];
  int b = blockIdx.x, tid = threadIdx.x;
  int i0 = b * cT + tid, i1 = i0 + 1024;
  float o0 = overlap[i0], o1 = overlap[i1];
  float mo = fmaxf(block_reduce_max(fmaxf(o0, o1), red), cEPS);
  float l0 = logits[i0] - o0 / mo;
  float l1 = logits[i1] - o1 / mo;
  float ml = block_reduce_max(fmaxf(l0, l1), red);
  float e0 = expf(l0 - ml), e1 = expf(l1 - ml);
  float S = block_reduce_sum(e0 + e1, red);
  float y0 = e0 / S, y1 = e1 / S;
  y[i0] = y0; y[i1] = y1;
  if (first_stage) { prev[i0] = y0; prev[i1] = y1; }
  else             { prev[i0] += y0; prev[i1] += y1; }
  if (tid < cDU) c_raw[b * cDU + tid] = 0.f;
  float ysr = block_reduce_sum(y0 + y1, red);
  float ysc = fmaxf(ysr, cEPS);
  float wsq = block_reduce_sum(y0 * unorm2[i0] + y1 * unorm2[i1], red);
  float yn0 = y0 / ysc, yn1 = y1 / ysc;
  float ent = block_reduce_sum(-yn0 * logf(fmaxf(yn0, cEPS)) - yn1 * logf(fmaxf(yn1, cEPS)), red);
  if (tid == 0) {
    scal[b * 8 + 0] = ysc;
    scal[b * 8 + 1] = ysr / (float)cT;
    scal[b * 8 + 2] = ent;
    scal[b * 8 + 3] = wsq;
  }
}

__global__ __launch_bounds__(256) void k_cen1(const float* __restrict__ y,
                                              const u16* __restrict__ ubf,
                                              const float* __restrict__ uf, int use_ubf,
                                              float* __restrict__ c_raw) {
  __shared__ float lds[4][512];
  int b = blockIdx.y, tc = blockIdx.x;
  int wv = threadIdx.x >> 6, lane = threadIdx.x & 63;
  float acc[8] = {};
  for (int i = 0; i < 16; ++i) {
    int row = b * cT + tc * 64 + wv * 16 + i;
    float yv = y[row];
    if (use_ubf) {
      u16x8 s = *(const u16x8*)(ubf + (size_t)row * cDU + lane * 8);
#pragma unroll
      for (int e = 0; e < 8; ++e) acc[e] += yv * bf2f(s[e]);
    } else {
      const float4* ur = (const float4*)(uf + (size_t)row * cDU);
      float4 a0 = ur[lane * 2], a1 = ur[lane * 2 + 1];
      acc[0] += yv * a0.x; acc[1] += yv * a0.y; acc[2] += yv * a0.z; acc[3] += yv * a0.w;
      acc[4] += yv * a1.x; acc[5] += yv * a1.y; acc[6] += yv * a1.z; acc[7] += yv * a1.w;
    }
  }
#pragma unroll
  for (int e = 0; e < 8; ++e) lds[wv][lane * 8 + e] = acc[e];
  __syncthreads();
  int d0 = threadIdx.x, d1 = threadIdx.x + 256;
  float s0 = lds[0][d0] + lds[1][d0] + lds[2][d0] + lds[3][d0];
  float s1 = lds[0][d1] + lds[1][d1] + lds[2][d1] + lds[3][d1];
  atomicAdd(&c_raw[b * cDU + d0], s0);
  atomicAdd(&c_raw[b * cDU + d1], s1);
}

__global__ __launch_bounds__(256) void k_zcen(const float* __restrict__ c_raw,
                                              const float* __restrict__ Wv,
                                              float* __restrict__ z,
                                              float* __restrict__ cnorm,
                                              float* __restrict__ scal) {
  if (blockIdx.x < 1024) {
    int wid = blockIdx.x * 4 + (threadIdx.x >> 6);
    int lane = threadIdx.x & 63;
    int b = wid >> 9, j = wid & 511;
    const float4* c4 = (const float4*)(c_raw + (size_t)b * cDU);
    const float4* w4 = (const float4*)(Wv + (size_t)j * cDU);
    float acc = dot4(c4[lane * 2], w4[lane * 2]) + dot4(c4[lane * 2 + 1], w4[lane * 2 + 1]);
    acc = wave_sum(acc);
    if (lane == 0) z[b * cDU + j] = acc;
  } else {
    __shared__ float red[256];
    int b = blockIdx.x - 1024, tid = threadIdx.x;
    float ysc = scal[b * 8 + 0];
    float c0 = c_raw[b * cDU + tid], c1 = c_raw[b * cDU + tid + 256];
    float n0 = c0 / ysc, n1 = c1 / ysc;
    cnorm[b * cDU + tid] = n0; cnorm[b * cDU + tid + 256] = n1;
    red[tid] = c0 * c0 + c1 * c1; __syncthreads();
    for (int s = 128; s; s >>= 1) { if (tid < s) red[tid] += red[tid + s]; __syncthreads(); }
    float csq = red[0]; __syncthreads();
    red[tid] = n0 * n0 + n1 * n1; __syncthreads();
    for (int s = 128; s; s >>= 1) { if (tid < s) red[tid] += red[tid + s]; __syncthreads(); }
    if (tid == 0) { scal[b * 8 + 6] = csq; scal[b * 8 + 7] = red[0]; }
  }
}

__global__ __launch_bounds__(256) void k_ydist(const u16* __restrict__ ubf,
                                               const float* __restrict__ uf, int use_ubf,
                                               const float* __restrict__ cnorm,
                                               const float* __restrict__ unorm2,
                                               const float* __restrict__ y,
                                               const float* __restrict__ scal,
                                               float* __restrict__ sprp) {
  __shared__ float s4[4];
  int b = blockIdx.y, tc = blockIdx.x;
  int wv = threadIdx.x >> 6, lane = threadIdx.x & 63;
  const float4* cr = (const float4*)(cnorm + (size_t)b * cDU);
  float4 cx0 = cr[lane * 2], cx1 = cr[lane * 2 + 1];
  float cen2 = scal[b * 8 + 7];
  float part = 0.f;
  for (int i = 0; i < 16; ++i) {
    int row = b * cT + tc * 64 + wv * 16 + i;
    float dot;
    if (use_ubf) {
      u16x8 s = *(const u16x8*)(ubf + (size_t)row * cDU + lane * 8);
      dot = bf2f(s[0]) * cx0.x + bf2f(s[1]) * cx0.y + bf2f(s[2]) * cx0.z + bf2f(s[3]) * cx0.w +
            bf2f(s[4]) * cx1.x + bf2f(s[5]) * cx1.y + bf2f(s[6]) * cx1.z + bf2f(s[7]) * cx1.w;
    } else {
      const float4* ur = (const float4*)(uf + (size_t)row * cDU);
      dot = dot4(ur[lane * 2], cx0) + dot4(ur[lane * 2 + 1], cx1);
    }
    dot = wave_sum(dot);
    if (lane == 0) {
      float d2 = unorm2[row] - 2.f * dot + cen2;
      part += y[row] * sqrtf(fmaxf(d2, 0.f));
    }
  }
  if (lane == 0) s4[wv] = part;
  __syncthreads();
  if (threadIdx.x == 0) sprp[b * 64 + tc * 2] = s4[0] + s4[1] + s4[2] + s4[3];
}

__global__ __launch_bounds__(256) void k_gru(const float* __restrict__ z,
                                             const float* __restrict__ scal,
                                             const float* __restrict__ sprp,
                                             const float* __restrict__ memin,
                                             float* __restrict__ memout,
                                             const float* __restrict__ W_ih,
                                             const float* __restrict__ b_ih,
                                             const float* __restrict__ W_hh,
                                             const float* __restrict__ b_hh,
                                             float* __restrict__ out, int stage) {
  int wid = blockIdx.x * 4 + (threadIdx.x >> 6);
  int lane = threadIdx.x & 63;
  int b = wid >> 9, i = wid & 511;
  const float4* xz = (const float4*)(z + (size_t)b * cDU);
  const float4* xm = (const float4*)(memin + (size_t)b * cDM);
  float4 z0 = xz[lane * 2], z1 = xz[lane * 2 + 1];
  float4 m0 = xm[lane * 2], m1 = xm[lane * 2 + 1];
  float ysc = scal[b * 8 + 0];
  float spr_raw = wave_sum(sprp[b * 64 + lane]);
  float aI[3], aH[3];
#pragma unroll
  for (int g = 0; g < 3; ++g) {
    size_t row = (size_t)(g * 512 + i);
    const float4* wI = (const float4*)(W_ih + row * 516);
    float a = dot4(z0, wI[lane * 2]) + dot4(z1, wI[lane * 2 + 1]);
    if (lane == 0) {
      float4 wt = wI[128];
      float cov = scal[b * 8 + 1], ent = scal[b * 8 + 2];
      float spr = spr_raw / ysc;
      float cmp = 2.f * (ysc * scal[b * 8 + 3] - scal[b * 8 + 6]) / fmaxf(ysc * ysc, cEPS);
      a += cov * wt.x + ent * wt.y + spr * wt.z + cmp * wt.w;
    }
    aI[g] = wave_sum(a);
    const float4* wH = (const float4*)(W_hh + row * cDM);
    float h = dot4(m0, wH[lane * 2]) + dot4(m1, wH[lane * 2 + 1]);
    aH[g] = wave_sum(h);
  }
  if (lane == 0) {
    float gir = aI[0] + b_ih[i],        ghr = aH[0] + b_hh[i];
    float giz = aI[1] + b_ih[512 + i],  ghz = aH[1] + b_hh[512 + i];
    float gin = aI[2] + b_ih[1024 + i], ghn = aH[2] + b_hh[1024 + i];
    float rg = 1.f / (1.f + expf(-(gir + ghr)));
    float zg = 1.f / (1.f + expf(-(giz + ghz)));
    float ng = tanhf(gin + rg * ghn);
    float mold = memin[b * cDM + i];
    memout[b * cDM + i] = (1.f - zg) * ng + zg * mold;
    out[(size_t)(b * cL + stage) * cDU + i] = z[b * cDU + i];
  }
}

extern "C" void kernel_launch(void* const* d_in, const int* in_sizes, int n_in,
                              void* d_out, int out_size, void* d_ws, size_t ws_size,
                              hipStream_t stream) {
  const float* u    = (const float*)d_in[0];
  const float* sf   = (const float*)d_in[1];
  const float* sim  = (const float*)d_in[2];
  const float* mem0 = (const float*)d_in[3];
  const float* Wq   = (const float*)d_in[4];
  const float* Wk   = (const float*)d_in[5];
  const float* Wv   = (const float*)d_in[6];
  const float* sbw1 = (const float*)d_in[7];
  const float* sbb1 = (const float*)d_in[8];
  const float* sbw2 = (const float*)d_in[9];
  const float* sbb2 = (const float*)d_in[10];
  const float* logt = (const float*)d_in[11];
  const float* W_ih = (const float*)d_in[12];
  const float* b_ih = (const float*)d_in[13];
  const float* W_hh = (const float*)d_in[14];
  const float* b_hh = (const float*)d_in[15];
  float* out = (float*)d_out;
  float* ws  = (float*)d_ws;
  u16* ubf   = (u16*)((char*)d_ws + U_OFFB);
  u16* simbf = (u16*)((char*)d_ws + SIM_OFFB);

  int use_ubf   = (ws_size >= WS_NEED_U) ? 1 : 0;
  int use_simbf = (ws_size >= WS_NEED_ALL) ? 1 : 0;

  // grid size: guaranteed-resident 256 blocks; 512 if occupancy allows 2/CU
  int grid = 256;
  int maxBlk = 0;
  if (hipOccupancyMaxActiveBlocksPerMultiprocessor(&maxBlk, mega, 256, 0) == hipSuccess &&
      maxBlk >= 2)
    grid = 512;

  void* args[] = {(void*)&u, (void*)&sf, (void*)&sim, (void*)&mem0,
                  (void*)&Wq, (void*)&Wk, (void*)&Wv,
                  (void*)&sbw1, (void*)&sbb1, (void*)&sbw2, (void*)&sbb2,
                  (void*)&logt, (void*)&W_ih, (void*)&b_ih, (void*)&W_hh, (void*)&b_hh,
                  (void*)&out, (void*)&ws, (void*)&ubf, (void*)&simbf,
                  (void*)&use_ubf, (void*)&use_simbf};
  hipError_t err = hipLaunchCooperativeKernel((void*)mega, dim3(grid), dim3(256),
                                              args, 0, stream);
  if (err == hipSuccess) return;

  // ---------------- fallback: proven round-3 multi-kernel path ----------------
  k_pre<<<(cB * cT) / 4, 256, 0, stream>>>(sf, u, sbw1, sbb1, sbw2, sbb2,
                                           ws + F_SB, ws + F_UN);
  if (use_ubf)
    k_cast<<<2048, 256, 0, stream>>>(u, sim, ubf, simbf, use_simbf);
  hipMemcpyAsync(ws + F_M0, mem0, (size_t)cB * cDM * sizeof(float),
                 hipMemcpyDeviceToDevice, stream);
  for (int stage = 0; stage < cL; ++stage) {
    float* mcur = ws + ((stage & 1) ? F_M1 : F_M0);
    float* mnxt = ws + ((stage & 1) ? F_M0 : F_M1);
    k_qqk<<<cB, 1024, 0, stream>>>(mcur, Wq, Wk, ws + F_QK);
    k_scores<<<4096, 256, 0, stream>>>(ubf, u, ws + F_QK, ws + F_SB, simbf, sim,
                                       ws + F_PR, logt, stage == 0 ? 0.0f : cGAMMA,
                                       use_ubf, use_simbf, ws + F_LG);
    k_softmax<<<cB, 1024, 0, stream>>>(ws + F_LG, ws + F_Y);
    k_overlap<<<4096, 256, 0, stream>>>(simbf, sim, ws + F_Y, use_simbf, ws + F_OV);
    k_soft2<<<cB, 1024, 0, stream>>>(ws + F_OV, ws + F_LG, ws + F_Y, ws + F_PR,
                                     ws + F_UN, ws + F_SC, ws + F_C, stage == 0 ? 1 : 0);
    k_cen1<<<dim3(32, cB), 256, 0, stream>>>(ws + F_Y, ubf, u, use_ubf, ws + F_C);
    k_zcen<<<1032, 256, 0, stream>>>(ws + F_C, Wv, ws + F_Z, ws + F_CN, ws + F_SC);
    // fallback k_ydist writes strided partials; zero unused slots first
    hipMemsetAsync(ws + F_SP, 0, 512 * sizeof(float), stream);
    k_ydist<<<dim3(32, cB), 256, 0, stream>>>(ubf, u, use_ubf, ws + F_CN, ws + F_UN,
                                              ws + F_Y, ws + F_SC, ws + F_SP);
    k_gru<<<1024, 256, 0, stream>>>(ws + F_Z, ws + F_SC, ws + F_SP, mcur, mnxt,
                                    W_ih, b_ih, W_hh, b_hh, out, stage);
  }
}

// Round 5
// 582.337 us; speedup vs baseline: 3.0347x; 3.0347x over previous
//
#include <hip/hip_runtime.h>
#include <math.h>

constexpr int cB = 8, cT = 2048, cDU = 512, cDM = 512, cDA = 256, cDF = 12, cL = 4;
constexpr float cEPS = 1e-6f;
constexpr float cSCALE = 16.0f;   // sqrt(DA)
constexpr float cGAMMA = 1.0f;

typedef unsigned short u16;
typedef unsigned char u8;
typedef u16 u16x8 __attribute__((ext_vector_type(8)));

// ---------------- workspace layout (float offsets) ----------------
constexpr size_t F_SB = 0;                 // sbias  B*T
constexpr size_t F_UN = F_SB + 16384;      // unorm2 B*T
constexpr size_t F_LG = F_UN + 16384;      // logits B*T
constexpr size_t F_Y  = F_LG + 16384;      // y (final, per stage) B*T
constexpr size_t F_PR = F_Y  + 16384;      // prev   B*T
constexpr size_t F_OV = F_PR + 16384;      // overlap B*T
constexpr size_t F_SP = F_OV + 16384;      // spread partials B*32
constexpr size_t F_QK = F_SP + 256;        // qk  B*DU
constexpr size_t F_M0 = F_QK + 4096;       // memory buf 0
constexpr size_t F_M1 = F_M0 + 4096;       // memory buf 1
constexpr size_t F_C  = F_M1 + 4096;       // c_raw B*DU
constexpr size_t F_CN = F_C  + 4096;       // cnorm B*DU
constexpr size_t F_Z  = F_CN + 4096;       // z B*DU
constexpr size_t F_SC = F_Z  + 4096;       // scalars B*8
constexpr size_t F_END = F_SC + 64;        // 123200 floats
constexpr size_t U_OFFB   = F_END * 4;                       // bf16 u
constexpr size_t U_BYTES  = (size_t)cB * cT * cDU * 2;
constexpr size_t S8_OFFB  = U_OFFB + U_BYTES;                // u8 sim
constexpr size_t S8_BYTES = (size_t)cB * cT * cT;
constexpr size_t WS_NEED_U   = S8_OFFB;
constexpr size_t WS_NEED_ALL = S8_OFFB + S8_BYTES;
// scal: 0 ysum_clamped, 1 coverage, 2 entropy, 3 wsq, 6 csq, 7 cen2

__device__ __forceinline__ float wave_sum(float v) {
#pragma unroll
  for (int o = 32; o; o >>= 1) v += __shfl_down(v, o);
  return v;   // valid on lane 0
}
__device__ __forceinline__ u16 f2bf(float f) {
  unsigned u = __float_as_uint(f);
  return (u16)((u + 0x7fffu + ((u >> 16) & 1u)) >> 16);
}
__device__ __forceinline__ float bf2f(u16 h) { return __uint_as_float(((unsigned)h) << 16); }
__device__ __forceinline__ float dot4(float4 a, float4 b) {
  return a.x * b.x + a.y * b.y + a.z * b.z + a.w * b.w;
}
__device__ __forceinline__ unsigned pack4(float a, float b, float c, float d) {
  unsigned b0 = (unsigned)(a * 255.f + 0.5f);
  unsigned b1 = (unsigned)(b * 255.f + 0.5f);
  unsigned b2 = (unsigned)(c * 255.f + 0.5f);
  unsigned b3 = (unsigned)(d * 255.f + 0.5f);
  return b0 | (b1 << 8) | (b2 << 16) | (b3 << 24);
}
// sd += dot of 4 u8 (in w) with float4 p
__device__ __forceinline__ void dotu8(float& sd, unsigned w, float4 p) {
  sd += (float)(w & 255u) * p.x + (float)((w >> 8) & 255u) * p.y +
        (float)((w >> 16) & 255u) * p.z + (float)(w >> 24) * p.w;
}

// =============== k_init: mem0 copy + u->bf16 + sim->u8 + sbias/unorm2 ===============
__global__ __launch_bounds__(256) void k_init(
    const float* __restrict__ u, const float* __restrict__ sf,
    const float* __restrict__ sim, const float* __restrict__ mem0,
    const float* __restrict__ w1, const float* __restrict__ b1,
    const float* __restrict__ w2, const float* __restrict__ b2,
    float* __restrict__ wsf, u16* __restrict__ ubf, u8* __restrict__ sim8,
    int use_ubf, int use_s8) {
  const int tid = threadIdx.x;
  const int gt = blockIdx.x * 256 + tid;
  const int nt = gridDim.x * 256;
  const int wv = tid >> 6, lane = tid & 63;
  const int gw = blockIdx.x * 4 + wv;
  const int nw = gridDim.x * 4;

  for (int i = gt; i < cB * cDM; i += nt) wsf[F_M0 + i] = mem0[i];

  if (use_ubf) {
    const int NU8 = cB * cT * cDU / 8;
    const float4* src = (const float4*)u;
    for (int c = gt; c < NU8; c += nt) {
      float4 f0 = src[(size_t)c * 2], f1 = src[(size_t)c * 2 + 1];
      u16x8 o;
      o[0] = f2bf(f0.x); o[1] = f2bf(f0.y); o[2] = f2bf(f0.z); o[3] = f2bf(f0.w);
      o[4] = f2bf(f1.x); o[5] = f2bf(f1.y); o[6] = f2bf(f1.z); o[7] = f2bf(f1.w);
      *(u16x8*)(ubf + (size_t)c * 8) = o;
    }
  }
  if (use_s8) {
    const int NS16 = (int)((size_t)cB * cT * cT / 16);
    const float4* src = (const float4*)sim;
    for (int c = gt; c < NS16; c += nt) {
      float4 f0 = src[(size_t)c * 4 + 0], f1 = src[(size_t)c * 4 + 1];
      float4 f2 = src[(size_t)c * 4 + 2], f3 = src[(size_t)c * 4 + 3];
      uint4 o;
      o.x = pack4(f0.x, f0.y, f0.z, f0.w);
      o.y = pack4(f1.x, f1.y, f1.z, f1.w);
      o.z = pack4(f2.x, f2.y, f2.z, f2.w);
      o.w = pack4(f3.x, f3.y, f3.z, f3.w);
      *(uint4*)(sim8 + (size_t)c * 16) = o;
    }
  }
  for (int row = gw; row < cB * cT; row += nw) {
    float d0 = sf[(size_t)row * cDF + 8];
    float d1 = sf[(size_t)row * cDF + 9];
    float d2 = sf[(size_t)row * cDF + 10];
    float acc = 0.f;
#pragma unroll
    for (int i = 0; i < 4; ++i) {
      int a = lane * 4 + i;
      float h = d0 * w1[a * 3 + 0] + d1 * w1[a * 3 + 1] + d2 * w1[a * 3 + 2] + b1[a];
      float g = 0.5f * h * (1.0f + erff(h * 0.70710678118654752f));
      acc += g * w2[a];
    }
    float un = 0.f;
    const float4* ur = (const float4*)(u + (size_t)row * cDU);
#pragma unroll
    for (int m = 0; m < 2; ++m) { float4 x = ur[lane + m * 64]; un += dot4(x, x); }
    acc = wave_sum(acc);
    un = wave_sum(un);
    if (lane == 0) { wsf[F_SB + row] = acc + b2[0]; wsf[F_UN + row] = un; }
  }
}

// =============== k_qqk: q = mem@Wq^T ; qk = Wk^T@q ; zero c_raw (block per b) ========
__global__ __launch_bounds__(1024) void k_qqk(const float* __restrict__ mem,
                                              const float* __restrict__ Wq,
                                              const float* __restrict__ Wk,
                                              float* __restrict__ qk,
                                              float* __restrict__ c_raw) {
  __shared__ float qs[cDA];
  __shared__ float red2[1024];
  int b = blockIdx.x, tid = threadIdx.x;
  int wv = tid >> 6, lane = tid & 63;
  if (tid < cDU) c_raw[b * cDU + tid] = 0.f;
  const float4* mr = (const float4*)(mem + (size_t)b * cDM);
  float4 m0 = mr[lane * 2], m1 = mr[lane * 2 + 1];
#pragma unroll
  for (int ii = 0; ii < 16; ++ii) {
    int a = wv * 16 + ii;
    const float4* wr = (const float4*)(Wq + (size_t)a * cDM);
    float acc = dot4(m0, wr[lane * 2]) + dot4(m1, wr[lane * 2 + 1]);
    acc = wave_sum(acc);
    if (lane == 0) qs[a] = acc;
  }
  __syncthreads();
  int j = tid & 511;
  int half = tid >> 9;
  float acc = 0.f;
#pragma unroll 4
  for (int a = half * 128; a < half * 128 + 128; ++a)
    acc += Wk[(size_t)a * cDU + j] * qs[a];
  red2[tid] = acc;
  __syncthreads();
  if (tid < 512) qk[b * cDU + j] = red2[tid] + red2[tid + 512];
}

// =============== k_scores: logits = (u.qk/SCALE + sbias - g*sim@prev)/temp ===========
__global__ __launch_bounds__(256) void k_scores(
    const u16* __restrict__ ubf, const float* __restrict__ uf,
    const float* __restrict__ qk, const float* __restrict__ sbias,
    const u8* __restrict__ sim8, const float* __restrict__ simf,
    const float* __restrict__ prev, const float* __restrict__ log_temp,
    float gamma, int use_ubf, int use_s8, float* __restrict__ logits) {
  int wid = (blockIdx.x * blockDim.x + threadIdx.x) >> 6;
  int lane = threadIdx.x & 63;
  int b = wid >> 11;
  const float4* qk4 = (const float4*)(qk + (size_t)b * cDU);
  float4 q0 = qk4[lane * 2], q1 = qk4[lane * 2 + 1];
  float acc;
  if (use_ubf) {
    u16x8 s = *(const u16x8*)(ubf + (size_t)wid * cDU + lane * 8);
    acc = bf2f(s[0]) * q0.x + bf2f(s[1]) * q0.y + bf2f(s[2]) * q0.z + bf2f(s[3]) * q0.w +
          bf2f(s[4]) * q1.x + bf2f(s[5]) * q1.y + bf2f(s[6]) * q1.z + bf2f(s[7]) * q1.w;
  } else {
    const float4* ur = (const float4*)(uf + (size_t)wid * cDU);
    acc = dot4(ur[lane * 2], q0) + dot4(ur[lane * 2 + 1], q1);
  }
  acc *= (1.0f / cSCALE);
  if (gamma != 0.0f) {
    float sd = 0.f;
    const float4* pr4 = (const float4*)(prev + (size_t)b * cT);
    if (use_s8) {
#pragma unroll
      for (int m = 0; m < 2; ++m) {
        uint4 sq = *(const uint4*)(sim8 + (size_t)wid * cT + m * 1024 + lane * 16);
        const float4* pb = pr4 + m * 256 + lane * 4;
        dotu8(sd, sq.x, pb[0]); dotu8(sd, sq.y, pb[1]);
        dotu8(sd, sq.z, pb[2]); dotu8(sd, sq.w, pb[3]);
      }
      sd *= (1.0f / 255.0f);
    } else {
      const float4* sr = (const float4*)(simf + (size_t)wid * cT);
#pragma unroll
      for (int m = 0; m < 8; ++m) sd += dot4(sr[lane + m * 64], pr4[lane + m * 64]);
    }
    acc -= gamma * sd;
  }
  acc = wave_sum(acc);
  if (lane == 0) {
    float temp = fminf(fmaxf(expf(log_temp[0]), 0.1f), 10.0f);
    logits[wid] = (acc + sbias[wid]) / temp;
  }
}

// =============== k_overlap: on-the-fly softmax(logits) + overlap = sim @ y1 ==========
// y1 is never materialized. Every block of batch b computes bit-identical m,S.
__global__ __launch_bounds__(256) void k_overlap(
    const u8* __restrict__ sim8, const float* __restrict__ simf,
    const float* __restrict__ logits, int use_s8, float* __restrict__ overlap) {
  __shared__ float ylds[2176];   // e values, padded: a = s + (s>>4)
  __shared__ float red[256];
  const int tid = threadIdx.x;
  const int wv = tid >> 6, lane = tid & 63;
  const int b = blockIdx.x >> 9;               // 512 blocks per b
  // --- softmax pre-phase over b's logits row ---
  float l[8];
  float mx = -INFINITY;
#pragma unroll
  for (int e = 0; e < 8; ++e) { l[e] = logits[b * cT + e * 256 + tid]; mx = fmaxf(mx, l[e]); }
  red[tid] = mx; __syncthreads();
  for (int s2 = 128; s2; s2 >>= 1) { if (tid < s2) red[tid] = fmaxf(red[tid], red[tid + s2]); __syncthreads(); }
  mx = red[0]; __syncthreads();
  float sum = 0.f;
#pragma unroll
  for (int e = 0; e < 8; ++e) {
    float ev = expf(l[e] - mx);
    sum += ev;
    int s = e * 256 + tid;
    ylds[s + (s >> 4)] = ev;
  }
  red[tid] = sum; __syncthreads();
  for (int s2 = 128; s2; s2 >>= 1) { if (tid < s2) red[tid] += red[tid + s2]; __syncthreads(); }
  float invS = 1.f / red[0];
  __syncthreads();
  // --- dot: each wave one row ---
  int row = blockIdx.x * 4 + wv;
  float acc = 0.f;
  if (use_s8) {
#pragma unroll
    for (int m = 0; m < 2; ++m) {
      uint4 sq = *(const uint4*)(sim8 + (size_t)row * cT + m * 1024 + lane * 16);
      int s0 = m * 1024 + lane * 16;
#pragma unroll
      for (int k = 0; k < 4; ++k) {
        unsigned w = (&sq.x)[k];
        int s = s0 + k * 4;
        acc += (float)(w & 255u)         * ylds[s + (s >> 4)] +
               (float)((w >> 8) & 255u)  * ylds[(s + 1) + ((s + 1) >> 4)] +
               (float)((w >> 16) & 255u) * ylds[(s + 2) + ((s + 2) >> 4)] +
               (float)(w >> 24)          * ylds[(s + 3) + ((s + 3) >> 4)];
      }
    }
    acc *= (1.0f / 255.0f);
  } else {
#pragma unroll
    for (int m = 0; m < 2; ++m) {
      const float4* sr = (const float4*)(simf + (size_t)row * cT + m * 1024 + lane * 16);
#pragma unroll
      for (int k = 0; k < 4; ++k) {
        float4 sv = sr[k];
        int s = m * 1024 + lane * 16 + k * 4;
        acc += sv.x * ylds[s + (s >> 4)] + sv.y * ylds[(s + 1) + ((s + 1) >> 4)] +
               sv.z * ylds[(s + 2) + ((s + 2) >> 4)] + sv.w * ylds[(s + 3) + ((s + 3) >> 4)];
      }
    }
  }
  acc = wave_sum(acc);
  if (lane == 0) overlap[row] = acc * invS;
}

// =============== k_statcen: penalty+resoftmax+stats (redundant per block) + centroid ==
// 256 blocks = (32 chunks, 8 b). Each block recomputes the full-row stats; chunk-0
// blocks write y/prev/scal; all blocks accumulate their 64-row chunk into c_raw.
__global__ __launch_bounds__(256) void k_statcen(
    const float* __restrict__ overlap, const float* __restrict__ logits,
    const float* __restrict__ unorm2,
    const u16* __restrict__ ubf, const float* __restrict__ uf, int use_ubf,
    float* __restrict__ y, float* __restrict__ prev,
    float* __restrict__ scal, float* __restrict__ c_raw, int first_stage) {
  __shared__ float ylds[2048];
  __shared__ float comb[2048];
  __shared__ float red[256];
  const int tid = threadIdx.x;
  const int wv = tid >> 6, lane = tid & 63;
  const int ch = blockIdx.x, b = blockIdx.y;
  float o[8], l[8], yv[8];
  float mo = -INFINITY;
#pragma unroll
  for (int e = 0; e < 8; ++e) { o[e] = overlap[b * cT + e * 256 + tid]; mo = fmaxf(mo, o[e]); }
  red[tid] = mo; __syncthreads();
  for (int s2 = 128; s2; s2 >>= 1) { if (tid < s2) red[tid] = fmaxf(red[tid], red[tid + s2]); __syncthreads(); }
  mo = fmaxf(red[0], cEPS); __syncthreads();
  float ml = -INFINITY;
#pragma unroll
  for (int e = 0; e < 8; ++e) { l[e] = logits[b * cT + e * 256 + tid] - o[e] / mo; ml = fmaxf(ml, l[e]); }
  red[tid] = ml; __syncthreads();
  for (int s2 = 128; s2; s2 >>= 1) { if (tid < s2) red[tid] = fmaxf(red[tid], red[tid + s2]); __syncthreads(); }
  ml = red[0]; __syncthreads();
  float sum = 0.f;
#pragma unroll
  for (int e = 0; e < 8; ++e) { l[e] = expf(l[e] - ml); sum += l[e]; }
  red[tid] = sum; __syncthreads();
  for (int s2 = 128; s2; s2 >>= 1) { if (tid < s2) red[tid] += red[tid + s2]; __syncthreads(); }
  float inv = 1.f / red[0]; __syncthreads();
  float ysr_p = 0.f, wsq_p = 0.f;
#pragma unroll
  for (int e = 0; e < 8; ++e) {
    yv[e] = l[e] * inv;
    ylds[e * 256 + tid] = yv[e];
    ysr_p += yv[e];
    wsq_p += yv[e] * unorm2[b * cT + e * 256 + tid];
  }
  red[tid] = ysr_p; __syncthreads();
  for (int s2 = 128; s2; s2 >>= 1) { if (tid < s2) red[tid] += red[tid + s2]; __syncthreads(); }
  float ysr = red[0]; __syncthreads();
  float ysc = fmaxf(ysr, cEPS);
  red[tid] = wsq_p; __syncthreads();
  for (int s2 = 128; s2; s2 >>= 1) { if (tid < s2) red[tid] += red[tid + s2]; __syncthreads(); }
  float wsq = red[0]; __syncthreads();
  float ent_p = 0.f;
#pragma unroll
  for (int e = 0; e < 8; ++e) {
    float yn = yv[e] / ysc;
    ent_p -= yn * logf(fmaxf(yn, cEPS));
  }
  red[tid] = ent_p; __syncthreads();
  for (int s2 = 128; s2; s2 >>= 1) { if (tid < s2) red[tid] += red[tid + s2]; __syncthreads(); }
  float ent = red[0]; __syncthreads();
  if (ch == 0) {
#pragma unroll
    for (int e = 0; e < 8; ++e) {
      int idx = b * cT + e * 256 + tid;
      y[idx] = yv[e];
      if (first_stage) prev[idx] = yv[e]; else prev[idx] += yv[e];
    }
    if (tid == 0) {
      scal[b * 8 + 0] = ysc;
      scal[b * 8 + 1] = ysr / (float)cT;
      scal[b * 8 + 2] = ent;
      scal[b * 8 + 3] = wsq;
    }
  }
  // --- chunk accumulation: c_raw += y @ u over rows [ch*64, ch*64+64) ---
  float acc[8] = {};
  for (int i = 0; i < 16; ++i) {
    int r = ch * 64 + wv * 16 + i;
    float yvv = ylds[r];
    int row = b * cT + r;
    if (use_ubf) {
      u16x8 s8 = *(const u16x8*)(ubf + (size_t)row * cDU + lane * 8);
#pragma unroll
      for (int e = 0; e < 8; ++e) acc[e] += yvv * bf2f(s8[e]);
    } else {
      const float4* ur = (const float4*)(uf + (size_t)row * cDU);
      float4 a0 = ur[lane * 2], a1 = ur[lane * 2 + 1];
      acc[0] += yvv * a0.x; acc[1] += yvv * a0.y; acc[2] += yvv * a0.z; acc[3] += yvv * a0.w;
      acc[4] += yvv * a1.x; acc[5] += yvv * a1.y; acc[6] += yvv * a1.z; acc[7] += yvv * a1.w;
    }
  }
  __syncthreads();
#pragma unroll
  for (int e = 0; e < 8; ++e) comb[wv * 512 + lane * 8 + e] = acc[e];
  __syncthreads();
  float s0 = comb[tid] + comb[512 + tid] + comb[1024 + tid] + comb[1536 + tid];
  float s1 = comb[tid + 256] + comb[512 + tid + 256] + comb[1024 + tid + 256] + comb[1536 + tid + 256];
  atomicAdd(&c_raw[b * cDU + tid], s0);
  atomicAdd(&c_raw[b * cDU + tid + 256], s1);
}

// =============== k_zcen: z = c_raw @ Wv^T ; centroid finalize =======================
__global__ __launch_bounds__(256) void k_zcen(const float* __restrict__ c_raw,
                                              const float* __restrict__ Wv,
                                              float* __restrict__ z,
                                              float* __restrict__ cnorm,
                                              float* __restrict__ scal) {
  if (blockIdx.x < 1024) {
    int wid = blockIdx.x * 4 + (threadIdx.x >> 6);
    int lane = threadIdx.x & 63;
    int b = wid >> 9, j = wid & 511;
    const float4* c4 = (const float4*)(c_raw + (size_t)b * cDU);
    const float4* w4 = (const float4*)(Wv + (size_t)j * cDU);
    float acc = dot4(c4[lane * 2], w4[lane * 2]) + dot4(c4[lane * 2 + 1], w4[lane * 2 + 1]);
    acc = wave_sum(acc);
    if (lane == 0) z[b * cDU + j] = acc;
  } else {
    __shared__ float red[256];
    int b = blockIdx.x - 1024, tid = threadIdx.x;
    float ysc = scal[b * 8 + 0];
    float c0 = c_raw[b * cDU + tid], c1 = c_raw[b * cDU + tid + 256];
    float n0 = c0 / ysc, n1 = c1 / ysc;
    cnorm[b * cDU + tid] = n0; cnorm[b * cDU + tid + 256] = n1;
    red[tid] = c0 * c0 + c1 * c1; __syncthreads();
    for (int s = 128; s; s >>= 1) { if (tid < s) red[tid] += red[tid + s]; __syncthreads(); }
    float csq = red[0]; __syncthreads();
    red[tid] = n0 * n0 + n1 * n1; __syncthreads();
    for (int s = 128; s; s >>= 1) { if (tid < s) red[tid] += red[tid + s]; __syncthreads(); }
    if (tid == 0) { scal[b * 8 + 6] = csq; scal[b * 8 + 7] = red[0]; }
  }
}

// =============== k_ydist: spread partials sprp[b*32+tc] (no atomics) =================
__global__ __launch_bounds__(256) void k_ydist(const u16* __restrict__ ubf,
                                               const float* __restrict__ uf, int use_ubf,
                                               const float* __restrict__ cnorm,
                                               const float* __restrict__ unorm2,
                                               const float* __restrict__ y,
                                               const float* __restrict__ scal,
                                               float* __restrict__ sprp) {
  __shared__ float s4[4];
  int b = blockIdx.y, tc = blockIdx.x;
  int wv = threadIdx.x >> 6, lane = threadIdx.x & 63;
  const float4* cr = (const float4*)(cnorm + (size_t)b * cDU);
  float4 cx0 = cr[lane * 2], cx1 = cr[lane * 2 + 1];
  float cen2 = scal[b * 8 + 7];
  float part = 0.f;
  for (int i = 0; i < 16; ++i) {
    int row = b * cT + tc * 64 + wv * 16 + i;
    float dot;
    if (use_ubf) {
      u16x8 s = *(const u16x8*)(ubf + (size_t)row * cDU + lane * 8);
      dot = bf2f(s[0]) * cx0.x + bf2f(s[1]) * cx0.y + bf2f(s[2]) * cx0.z + bf2f(s[3]) * cx0.w +
            bf2f(s[4]) * cx1.x + bf2f(s[5]) * cx1.y + bf2f(s[6]) * cx1.z + bf2f(s[7]) * cx1.w;
    } else {
      const float4* ur = (const float4*)(uf + (size_t)row * cDU);
      dot = dot4(ur[lane * 2], cx0) + dot4(ur[lane * 2 + 1], cx1);
    }
    dot = wave_sum(dot);
    if (lane == 0) {
      float d2 = unorm2[row] - 2.f * dot + cen2;
      part += y[row] * sqrtf(fmaxf(d2, 0.f));
    }
  }
  if (lane == 0) s4[wv] = part;
  __syncthreads();
  if (threadIdx.x == 0) sprp[b * 32 + tc] = s4[0] + s4[1] + s4[2] + s4[3];
}

// =============== k_gru: gates + memory update + output (wave per (b,i)) ==============
__global__ __launch_bounds__(256) void k_gru(const float* __restrict__ z,
                                             const float* __restrict__ scal,
                                             const float* __restrict__ sprp,
                                             const float* __restrict__ memin,
                                             float* __restrict__ memout,
                                             const float* __restrict__ W_ih,
                                             const float* __restrict__ b_ih,
                                             const float* __restrict__ W_hh,
                                             const float* __restrict__ b_hh,
                                             float* __restrict__ out, int stage) {
  int wid = blockIdx.x * 4 + (threadIdx.x >> 6);
  int lane = threadIdx.x & 63;
  int b = wid >> 9, i = wid & 511;
  const float4* xz = (const float4*)(z + (size_t)b * cDU);
  const float4* xm = (const float4*)(memin + (size_t)b * cDM);
  float4 z0 = xz[lane * 2], z1 = xz[lane * 2 + 1];
  float4 m0 = xm[lane * 2], m1 = xm[lane * 2 + 1];
  float ysc = scal[b * 8 + 0];
  float sv = (lane < 32) ? sprp[b * 32 + lane] : 0.f;
  float spr_raw = wave_sum(sv);
  float aI[3], aH[3];
#pragma unroll
  for (int g = 0; g < 3; ++g) {
    size_t row = (size_t)(g * 512 + i);
    const float4* wI = (const float4*)(W_ih + row * 516);
    float a = dot4(z0, wI[lane * 2]) + dot4(z1, wI[lane * 2 + 1]);
    if (lane == 0) {
      float4 wt = wI[128];
      float cov = scal[b * 8 + 1], ent = scal[b * 8 + 2];
      float spr = spr_raw / ysc;
      float cmp = 2.f * (ysc * scal[b * 8 + 3] - scal[b * 8 + 6]) / fmaxf(ysc * ysc, cEPS);
      a += cov * wt.x + ent * wt.y + spr * wt.z + cmp * wt.w;
    }
    aI[g] = wave_sum(a);
    const float4* wH = (const float4*)(W_hh + row * cDM);
    float h = dot4(m0, wH[lane * 2]) + dot4(m1, wH[lane * 2 + 1]);
    aH[g] = wave_sum(h);
  }
  if (lane == 0) {
    float gir = aI[0] + b_ih[i],        ghr = aH[0] + b_hh[i];
    float giz = aI[1] + b_ih[512 + i],  ghz = aH[1] + b_hh[512 + i];
    float gin = aI[2] + b_ih[1024 + i], ghn = aH[2] + b_hh[1024 + i];
    float rg = 1.f / (1.f + expf(-(gir + ghr)));
    float zg = 1.f / (1.f + expf(-(giz + ghz)));
    float ng = tanhf(gin + rg * ghn);
    float mold = memin[b * cDM + i];
    memout[b * cDM + i] = (1.f - zg) * ng + zg * mold;
    out[(size_t)(b * cL + stage) * cDU + i] = z[b * cDU + i];
  }
}

extern "C" void kernel_launch(void* const* d_in, const int* in_sizes, int n_in,
                              void* d_out, int out_size, void* d_ws, size_t ws_size,
                              hipStream_t stream) {
  const float* u    = (const float*)d_in[0];
  const float* sf   = (const float*)d_in[1];
  const float* sim  = (const float*)d_in[2];
  const float* mem0 = (const float*)d_in[3];
  const float* Wq   = (const float*)d_in[4];
  const float* Wk   = (const float*)d_in[5];
  const float* Wv   = (const float*)d_in[6];
  const float* sbw1 = (const float*)d_in[7];
  const float* sbb1 = (const float*)d_in[8];
  const float* sbw2 = (const float*)d_in[9];
  const float* sbb2 = (const float*)d_in[10];
  const float* logt = (const float*)d_in[11];
  const float* W_ih = (const float*)d_in[12];
  const float* b_ih = (const float*)d_in[13];
  const float* W_hh = (const float*)d_in[14];
  const float* b_hh = (const float*)d_in[15];
  float* out = (float*)d_out;
  float* ws  = (float*)d_ws;
  u16* ubf  = (u16*)((char*)d_ws + U_OFFB);
  u8* sim8  = (u8*)((char*)d_ws + S8_OFFB);

  const int use_ubf = (ws_size >= WS_NEED_U) ? 1 : 0;
  const int use_s8  = (ws_size >= WS_NEED_ALL) ? 1 : 0;

  k_init<<<2048, 256, 0, stream>>>(u, sf, sim, mem0, sbw1, sbb1, sbw2, sbb2,
                                   ws, ubf, sim8, use_ubf, use_s8);

  for (int stage = 0; stage < cL; ++stage) {
    float* mcur = ws + ((stage & 1) ? F_M1 : F_M0);
    float* mnxt = ws + ((stage & 1) ? F_M0 : F_M1);
    k_qqk<<<cB, 1024, 0, stream>>>(mcur, Wq, Wk, ws + F_QK, ws + F_C);
    k_scores<<<4096, 256, 0, stream>>>(ubf, u, ws + F_QK, ws + F_SB, sim8, sim,
                                       ws + F_PR, logt, stage == 0 ? 0.0f : cGAMMA,
                                       use_ubf, use_s8, ws + F_LG);
    k_overlap<<<4096, 256, 0, stream>>>(sim8, sim, ws + F_LG, use_s8, ws + F_OV);
    k_statcen<<<dim3(32, cB), 256, 0, stream>>>(ws + F_OV, ws + F_LG, ws + F_UN,
                                                ubf, u, use_ubf,
                                                ws + F_Y, ws + F_PR, ws + F_SC, ws + F_C,
                                                stage == 0 ? 1 : 0);
    k_zcen<<<1032, 256, 0, stream>>>(ws + F_C, Wv, ws + F_Z, ws + F_CN, ws + F_SC);
    k_ydist<<<dim3(32, cB), 256, 0, stream>>>(ubf, u, use_ubf, ws + F_CN, ws + F_UN,
                                              ws + F_Y, ws + F_SC, ws + F_SP);
    k_gru<<<1024, 256, 0, stream>>>(ws + F_Z, ws + F_SC, ws + F_SP, mcur, mnxt,
                                    W_ih, b_ih, W_hh, b_hh, out, stage);
  }
}

// Round 6
// 568.370 us; speedup vs baseline: 3.1093x; 1.0246x over previous
//
#include <hip/hip_runtime.h>
#include <math.h>

constexpr int cB = 8, cT = 2048, cDU = 512, cDM = 512, cDA = 256, cDF = 12, cL = 4;
constexpr float cEPS = 1e-6f;
constexpr float cSCALE = 16.0f;   // sqrt(DA)
constexpr float cGAMMA = 1.0f;

typedef unsigned short u16;
typedef unsigned char u8;
typedef u16 u16x8 __attribute__((ext_vector_type(8)));

// ---------------- workspace layout (float offsets) ----------------
constexpr size_t F_SB = 0;                 // sbias  B*T
constexpr size_t F_UN = F_SB + 16384;      // unorm2 B*T
constexpr size_t F_LG = F_UN + 16384;      // logits B*T
constexpr size_t F_Y  = F_LG + 16384;      // y (final, per stage) B*T
constexpr size_t F_PR = F_Y  + 16384;      // prev   B*T
constexpr size_t F_OV = F_PR + 16384;      // overlap B*T
constexpr size_t F_SP = F_OV + 16384;      // spread partials B*32
constexpr size_t F_QK = F_SP + 256;        // qk  B*DU
constexpr size_t F_M0 = F_QK + 4096;       // memory buf 0
constexpr size_t F_M1 = F_M0 + 4096;       // memory buf 1
constexpr size_t F_C  = F_M1 + 4096;       // c_raw B*DU
constexpr size_t F_Z  = F_C  + 4096;       // z B*DU
constexpr size_t F_SC = F_Z  + 4096;       // scalars B*8
constexpr size_t F_END = F_SC + 64;
constexpr size_t U_OFFB   = F_END * 4;                       // bf16 u
constexpr size_t U_BYTES  = (size_t)cB * cT * cDU * 2;
constexpr size_t S8_OFFB  = U_OFFB + U_BYTES;                // u8 sim
constexpr size_t S8_BYTES = (size_t)cB * cT * cT;
constexpr size_t WS_NEED_U   = S8_OFFB;
constexpr size_t WS_NEED_ALL = S8_OFFB + S8_BYTES;
// scal: 0 ysum_clamped, 1 coverage, 2 entropy, 3 wsq, 6 csq

__device__ __forceinline__ float wave_sum(float v) {
#pragma unroll
  for (int o = 32; o; o >>= 1) v += __shfl_down(v, o);
  return v;   // valid on lane 0
}
__device__ __forceinline__ u16 f2bf(float f) {
  unsigned u = __float_as_uint(f);
  return (u16)((u + 0x7fffu + ((u >> 16) & 1u)) >> 16);
}
__device__ __forceinline__ float bf2f(u16 h) { return __uint_as_float(((unsigned)h) << 16); }
__device__ __forceinline__ float dot4(float4 a, float4 b) {
  return a.x * b.x + a.y * b.y + a.z * b.z + a.w * b.w;
}
__device__ __forceinline__ unsigned pack4(float a, float b, float c, float d) {
  unsigned b0 = (unsigned)(a * 255.f + 0.5f);
  unsigned b1 = (unsigned)(b * 255.f + 0.5f);
  unsigned b2 = (unsigned)(c * 255.f + 0.5f);
  unsigned b3 = (unsigned)(d * 255.f + 0.5f);
  return b0 | (b1 << 8) | (b2 << 16) | (b3 << 24);
}
__device__ __forceinline__ void dotu8(float& sd, unsigned w, float4 p) {
  sd += (float)(w & 255u) * p.x + (float)((w >> 8) & 255u) * p.y +
        (float)((w >> 16) & 255u) * p.z + (float)(w >> 24) * p.w;
}

// =============== k_init: mem0 copy + u->bf16 + sbias/unorm2 (NO sim pass) ============
__global__ __launch_bounds__(256) void k_init(
    const float* __restrict__ u, const float* __restrict__ sf,
    const float* __restrict__ mem0,
    const float* __restrict__ w1, const float* __restrict__ b1,
    const float* __restrict__ w2, const float* __restrict__ b2,
    float* __restrict__ wsf, u16* __restrict__ ubf, int use_ubf) {
  const int tid = threadIdx.x;
  const int gt = blockIdx.x * 256 + tid;
  const int nt = gridDim.x * 256;
  const int wv = tid >> 6, lane = tid & 63;
  const int gw = blockIdx.x * 4 + wv;
  const int nw = gridDim.x * 4;

  for (int i = gt; i < cB * cDM; i += nt) wsf[F_M0 + i] = mem0[i];

  if (use_ubf) {
    const int NU8 = cB * cT * cDU / 8;
    const float4* src = (const float4*)u;
    for (int c = gt; c < NU8; c += nt) {
      float4 f0 = src[(size_t)c * 2], f1 = src[(size_t)c * 2 + 1];
      u16x8 o;
      o[0] = f2bf(f0.x); o[1] = f2bf(f0.y); o[2] = f2bf(f0.z); o[3] = f2bf(f0.w);
      o[4] = f2bf(f1.x); o[5] = f2bf(f1.y); o[6] = f2bf(f1.z); o[7] = f2bf(f1.w);
      *(u16x8*)(ubf + (size_t)c * 8) = o;
    }
  }
  for (int row = gw; row < cB * cT; row += nw) {
    float d0 = sf[(size_t)row * cDF + 8];
    float d1 = sf[(size_t)row * cDF + 9];
    float d2 = sf[(size_t)row * cDF + 10];
    float acc = 0.f;
#pragma unroll
    for (int i = 0; i < 4; ++i) {
      int a = lane * 4 + i;
      float h = d0 * w1[a * 3 + 0] + d1 * w1[a * 3 + 1] + d2 * w1[a * 3 + 2] + b1[a];
      float g = 0.5f * h * (1.0f + erff(h * 0.70710678118654752f));
      acc += g * w2[a];
    }
    float un = 0.f;
    const float4* ur = (const float4*)(u + (size_t)row * cDU);
#pragma unroll
    for (int m = 0; m < 2; ++m) { float4 x = ur[lane + m * 64]; un += dot4(x, x); }
    acc = wave_sum(acc);
    un = wave_sum(un);
    if (lane == 0) { wsf[F_SB + row] = acc + b2[0]; wsf[F_UN + row] = un; }
  }
}

// =============== k_qqk: q = mem@Wq^T ; qk = Wk^T@q ; zero c_raw (block per b) ========
__global__ __launch_bounds__(1024) void k_qqk(const float* __restrict__ mem,
                                              const float* __restrict__ Wq,
                                              const float* __restrict__ Wk,
                                              float* __restrict__ qk,
                                              float* __restrict__ c_raw) {
  __shared__ float qs[cDA];
  __shared__ float red2[1024];
  int b = blockIdx.x, tid = threadIdx.x;
  int wv = tid >> 6, lane = tid & 63;
  if (tid < cDU) c_raw[b * cDU + tid] = 0.f;
  const float4* mr = (const float4*)(mem + (size_t)b * cDM);
  float4 m0 = mr[lane * 2], m1 = mr[lane * 2 + 1];
#pragma unroll
  for (int ii = 0; ii < 16; ++ii) {
    int a = wv * 16 + ii;
    const float4* wr = (const float4*)(Wq + (size_t)a * cDM);
    float acc = dot4(m0, wr[lane * 2]) + dot4(m1, wr[lane * 2 + 1]);
    acc = wave_sum(acc);
    if (lane == 0) qs[a] = acc;
  }
  __syncthreads();
  int j = tid & 511;
  int half = tid >> 9;
  float acc = 0.f;
#pragma unroll 4
  for (int a = half * 128; a < half * 128 + 128; ++a)
    acc += Wk[(size_t)a * cDU + j] * qs[a];
  red2[tid] = acc;
  __syncthreads();
  if (tid < 512) qk[b * cDU + j] = red2[tid] + red2[tid + 512];
}

// =============== k_scores: logits = (u.qk/SCALE + sbias - g*sim@prev)/temp ===========
__global__ __launch_bounds__(256) void k_scores(
    const u16* __restrict__ ubf, const float* __restrict__ uf,
    const float* __restrict__ qk, const float* __restrict__ sbias,
    const u8* __restrict__ sim8, const float* __restrict__ simf,
    const float* __restrict__ prev, const float* __restrict__ log_temp,
    float gamma, int use_ubf, int use_s8, float* __restrict__ logits) {
  int wid = (blockIdx.x * blockDim.x + threadIdx.x) >> 6;
  int lane = threadIdx.x & 63;
  int b = wid >> 11;
  const float4* qk4 = (const float4*)(qk + (size_t)b * cDU);
  float4 q0 = qk4[lane * 2], q1 = qk4[lane * 2 + 1];
  float acc;
  if (use_ubf) {
    u16x8 s = *(const u16x8*)(ubf + (size_t)wid * cDU + lane * 8);
    acc = bf2f(s[0]) * q0.x + bf2f(s[1]) * q0.y + bf2f(s[2]) * q0.z + bf2f(s[3]) * q0.w +
          bf2f(s[4]) * q1.x + bf2f(s[5]) * q1.y + bf2f(s[6]) * q1.z + bf2f(s[7]) * q1.w;
  } else {
    const float4* ur = (const float4*)(uf + (size_t)wid * cDU);
    acc = dot4(ur[lane * 2], q0) + dot4(ur[lane * 2 + 1], q1);
  }
  acc *= (1.0f / cSCALE);
  if (gamma != 0.0f) {
    float sd = 0.f;
    const float4* pr4 = (const float4*)(prev + (size_t)b * cT);
    if (use_s8) {
#pragma unroll
      for (int m = 0; m < 2; ++m) {
        uint4 sq = *(const uint4*)(sim8 + (size_t)wid * cT + m * 1024 + lane * 16);
        const float4* pb = pr4 + m * 256 + lane * 4;
        dotu8(sd, sq.x, pb[0]); dotu8(sd, sq.y, pb[1]);
        dotu8(sd, sq.z, pb[2]); dotu8(sd, sq.w, pb[3]);
      }
      sd *= (1.0f / 255.0f);
    } else {
      const float4* sr = (const float4*)(simf + (size_t)wid * cT);
#pragma unroll
      for (int m = 0; m < 8; ++m) sd += dot4(sr[lane + m * 64], pr4[lane + m * 64]);
    }
    acc -= gamma * sd;
  }
  acc = wave_sum(acc);
  if (lane == 0) {
    float temp = fminf(fmaxf(expf(log_temp[0]), 0.1f), 10.0f);
    logits[wid] = (acc + sbias[wid]) / temp;
  }
}

// =============== k_overlap: softmax(logits) on the fly + overlap = sim @ y1 ==========
// convert!=0 (stage 0, use_s8): read fp32 sim, ALSO write u8 sim for later stages.
__global__ __launch_bounds__(256) void k_overlap(
    const u8* __restrict__ sim8c, u8* __restrict__ sim8w,
    const float* __restrict__ simf,
    const float* __restrict__ logits, int use_s8, int convert,
    float* __restrict__ overlap) {
  __shared__ float ylds[2176];   // padded: a = s + (s>>4)
  __shared__ float red[256];
  const int tid = threadIdx.x;
  const int wv = tid >> 6, lane = tid & 63;
  const int b = blockIdx.x >> 9;               // 512 blocks per b
  float l[8];
  float mx = -INFINITY;
#pragma unroll
  for (int e = 0; e < 8; ++e) { l[e] = logits[b * cT + e * 256 + tid]; mx = fmaxf(mx, l[e]); }
  red[tid] = mx; __syncthreads();
  for (int s2 = 128; s2; s2 >>= 1) { if (tid < s2) red[tid] = fmaxf(red[tid], red[tid + s2]); __syncthreads(); }
  mx = red[0]; __syncthreads();
  float sum = 0.f;
#pragma unroll
  for (int e = 0; e < 8; ++e) {
    float ev = expf(l[e] - mx);
    sum += ev;
    int s = e * 256 + tid;
    ylds[s + (s >> 4)] = ev;
  }
  red[tid] = sum; __syncthreads();
  for (int s2 = 128; s2; s2 >>= 1) { if (tid < s2) red[tid] += red[tid + s2]; __syncthreads(); }
  float invS = 1.f / red[0];
  __syncthreads();
  int row = blockIdx.x * 4 + wv;
  float acc = 0.f;
  if (use_s8 && !convert) {
#pragma unroll
    for (int m = 0; m < 2; ++m) {
      uint4 sq = *(const uint4*)(sim8c + (size_t)row * cT + m * 1024 + lane * 16);
      int s0 = m * 1024 + lane * 16;
#pragma unroll
      for (int k = 0; k < 4; ++k) {
        unsigned w = (&sq.x)[k];
        int s = s0 + k * 4;
        acc += (float)(w & 255u)         * ylds[s + (s >> 4)] +
               (float)((w >> 8) & 255u)  * ylds[(s + 1) + ((s + 1) >> 4)] +
               (float)((w >> 16) & 255u) * ylds[(s + 2) + ((s + 2) >> 4)] +
               (float)(w >> 24)          * ylds[(s + 3) + ((s + 3) >> 4)];
      }
    }
    acc *= (1.0f / 255.0f);
  } else {
#pragma unroll
    for (int m = 0; m < 2; ++m) {
      const float4* sr = (const float4*)(simf + (size_t)row * cT + m * 1024 + lane * 16);
      uint4 oq;
#pragma unroll
      for (int k = 0; k < 4; ++k) {
        float4 sv = sr[k];
        int s = m * 1024 + lane * 16 + k * 4;
        acc += sv.x * ylds[s + (s >> 4)] + sv.y * ylds[(s + 1) + ((s + 1) >> 4)] +
               sv.z * ylds[(s + 2) + ((s + 2) >> 4)] + sv.w * ylds[(s + 3) + ((s + 3) >> 4)];
        (&oq.x)[k] = pack4(sv.x, sv.y, sv.z, sv.w);
      }
      if (convert)
        *(uint4*)(sim8w + (size_t)row * cT + m * 1024 + lane * 16) = oq;
    }
  }
  acc = wave_sum(acc);
  if (lane == 0) overlap[row] = acc * invS;
}

// =============== k_statcen: penalty+resoftmax+stats + centroid chunk accum ===========
__global__ __launch_bounds__(256) void k_statcen(
    const float* __restrict__ overlap, const float* __restrict__ logits,
    const float* __restrict__ unorm2,
    const u16* __restrict__ ubf, const float* __restrict__ uf, int use_ubf,
    float* __restrict__ y, float* __restrict__ prev,
    float* __restrict__ scal, float* __restrict__ c_raw, int first_stage) {
  __shared__ float ylds[2048];
  __shared__ float comb[2048];
  __shared__ float red[256];
  const int tid = threadIdx.x;
  const int wv = tid >> 6, lane = tid & 63;
  const int ch = blockIdx.x, b = blockIdx.y;
  float o[8], l[8], yv[8];
  float mo = -INFINITY;
#pragma unroll
  for (int e = 0; e < 8; ++e) { o[e] = overlap[b * cT + e * 256 + tid]; mo = fmaxf(mo, o[e]); }
  red[tid] = mo; __syncthreads();
  for (int s2 = 128; s2; s2 >>= 1) { if (tid < s2) red[tid] = fmaxf(red[tid], red[tid + s2]); __syncthreads(); }
  mo = fmaxf(red[0], cEPS); __syncthreads();
  float ml = -INFINITY;
#pragma unroll
  for (int e = 0; e < 8; ++e) { l[e] = logits[b * cT + e * 256 + tid] - o[e] / mo; ml = fmaxf(ml, l[e]); }
  red[tid] = ml; __syncthreads();
  for (int s2 = 128; s2; s2 >>= 1) { if (tid < s2) red[tid] = fmaxf(red[tid], red[tid + s2]); __syncthreads(); }
  ml = red[0]; __syncthreads();
  float sum = 0.f;
#pragma unroll
  for (int e = 0; e < 8; ++e) { l[e] = expf(l[e] - ml); sum += l[e]; }
  red[tid] = sum; __syncthreads();
  for (int s2 = 128; s2; s2 >>= 1) { if (tid < s2) red[tid] += red[tid + s2]; __syncthreads(); }
  float inv = 1.f / red[0]; __syncthreads();
  float ysr_p = 0.f, wsq_p = 0.f;
#pragma unroll
  for (int e = 0; e < 8; ++e) {
    yv[e] = l[e] * inv;
    ylds[e * 256 + tid] = yv[e];
    ysr_p += yv[e];
    wsq_p += yv[e] * unorm2[b * cT + e * 256 + tid];
  }
  red[tid] = ysr_p; __syncthreads();
  for (int s2 = 128; s2; s2 >>= 1) { if (tid < s2) red[tid] += red[tid + s2]; __syncthreads(); }
  float ysr = red[0]; __syncthreads();
  float ysc = fmaxf(ysr, cEPS);
  red[tid] = wsq_p; __syncthreads();
  for (int s2 = 128; s2; s2 >>= 1) { if (tid < s2) red[tid] += red[tid + s2]; __syncthreads(); }
  float wsq = red[0]; __syncthreads();
  float ent_p = 0.f;
#pragma unroll
  for (int e = 0; e < 8; ++e) {
    float yn = yv[e] / ysc;
    ent_p -= yn * logf(fmaxf(yn, cEPS));
  }
  red[tid] = ent_p; __syncthreads();
  for (int s2 = 128; s2; s2 >>= 1) { if (tid < s2) red[tid] += red[tid + s2]; __syncthreads(); }
  float ent = red[0]; __syncthreads();
  if (ch == 0) {
#pragma unroll
    for (int e = 0; e < 8; ++e) {
      int idx = b * cT + e * 256 + tid;
      y[idx] = yv[e];
      if (first_stage) prev[idx] = yv[e]; else prev[idx] += yv[e];
    }
    if (tid == 0) {
      scal[b * 8 + 0] = ysc;
      scal[b * 8 + 1] = ysr / (float)cT;
      scal[b * 8 + 2] = ent;
      scal[b * 8 + 3] = wsq;
    }
  }
  float acc[8] = {};
  for (int i = 0; i < 16; ++i) {
    int r = ch * 64 + wv * 16 + i;
    float yvv = ylds[r];
    int row = b * cT + r;
    if (use_ubf) {
      u16x8 s8 = *(const u16x8*)(ubf + (size_t)row * cDU + lane * 8);
#pragma unroll
      for (int e = 0; e < 8; ++e) acc[e] += yvv * bf2f(s8[e]);
    } else {
      const float4* ur = (const float4*)(uf + (size_t)row * cDU);
      float4 a0 = ur[lane * 2], a1 = ur[lane * 2 + 1];
      acc[0] += yvv * a0.x; acc[1] += yvv * a0.y; acc[2] += yvv * a0.z; acc[3] += yvv * a0.w;
      acc[4] += yvv * a1.x; acc[5] += yvv * a1.y; acc[6] += yvv * a1.z; acc[7] += yvv * a1.w;
    }
  }
  __syncthreads();
#pragma unroll
  for (int e = 0; e < 8; ++e) comb[wv * 512 + lane * 8 + e] = acc[e];
  __syncthreads();
  float s0 = comb[tid] + comb[512 + tid] + comb[1024 + tid] + comb[1536 + tid];
  float s1 = comb[tid + 256] + comb[512 + tid + 256] + comb[1024 + tid + 256] + comb[1536 + tid + 256];
  atomicAdd(&c_raw[b * cDU + tid], s0);
  atomicAdd(&c_raw[b * cDU + tid + 256], s1);
}

// =============== k_zyd: blocks 0..1023 -> z = c_raw@Wv^T ; 1024..1279 -> spread ======
__global__ __launch_bounds__(256) void k_zyd(
    const float* __restrict__ c_raw, const float* __restrict__ Wv,
    const u16* __restrict__ ubf, const float* __restrict__ uf, int use_ubf,
    const float* __restrict__ unorm2, const float* __restrict__ y,
    float* __restrict__ z, float* __restrict__ scal, float* __restrict__ sprp) {
  __shared__ float s4[4];
  int wv = threadIdx.x >> 6, lane = threadIdx.x & 63;
  if (blockIdx.x < 1024) {
    int wid = blockIdx.x * 4 + wv;
    int b = wid >> 9, j = wid & 511;
    const float4* c4 = (const float4*)(c_raw + (size_t)b * cDU);
    const float4* w4 = (const float4*)(Wv + (size_t)j * cDU);
    float acc = dot4(c4[lane * 2], w4[lane * 2]) + dot4(c4[lane * 2 + 1], w4[lane * 2 + 1]);
    acc = wave_sum(acc);
    if (lane == 0) z[b * cDU + j] = acc;
    return;
  }
  int unit = blockIdx.x - 1024;   // 0..255
  int b = unit >> 5, tc = unit & 31;
  float ysc = scal[b * 8 + 0];
  float inv = 1.f / ysc;
  const float4* c4 = (const float4*)(c_raw + (size_t)b * cDU);
  float4 cr0 = c4[lane * 2], cr1 = c4[lane * 2 + 1];
  float4 cx0, cx1;
  cx0.x = cr0.x * inv; cx0.y = cr0.y * inv; cx0.z = cr0.z * inv; cx0.w = cr0.w * inv;
  cx1.x = cr1.x * inv; cx1.y = cr1.y * inv; cx1.z = cr1.z * inv; cx1.w = cr1.w * inv;
  float cen2 = wave_sum(dot4(cx0, cx0) + dot4(cx1, cx1));     // lane0-valid
  if (tc == 0 && wv == 0) {
    float csq = wave_sum(dot4(cr0, cr0) + dot4(cr1, cr1));
    if (lane == 0) scal[b * 8 + 6] = csq;
  }
  float part = 0.f;
  for (int i = 0; i < 16; ++i) {
    int row = b * cT + tc * 64 + wv * 16 + i;
    float dot;
    if (use_ubf) {
      u16x8 s = *(const u16x8*)(ubf + (size_t)row * cDU + lane * 8);
      dot = bf2f(s[0]) * cx0.x + bf2f(s[1]) * cx0.y + bf2f(s[2]) * cx0.z + bf2f(s[3]) * cx0.w +
            bf2f(s[4]) * cx1.x + bf2f(s[5]) * cx1.y + bf2f(s[6]) * cx1.z + bf2f(s[7]) * cx1.w;
    } else {
      const float4* ur = (const float4*)(uf + (size_t)row * cDU);
      dot = dot4(ur[lane * 2], cx0) + dot4(ur[lane * 2 + 1], cx1);
    }
    dot = wave_sum(dot);
    if (lane == 0) {
      float d2 = unorm2[row] - 2.f * dot + cen2;
      part += y[row] * sqrtf(fmaxf(d2, 0.f));
    }
  }
  if (lane == 0) s4[wv] = part;
  __syncthreads();
  if (threadIdx.x == 0) sprp[b * 32 + tc] = s4[0] + s4[1] + s4[2] + s4[3];
}

// =============== k_gru: gates + memory update + output (wave per (b,i)) ==============
__global__ __launch_bounds__(256) void k_gru(const float* __restrict__ z,
                                             const float* __restrict__ scal,
                                             const float* __restrict__ sprp,
                                             const float* __restrict__ memin,
                                             float* __restrict__ memout,
                                             const float* __restrict__ W_ih,
                                             const float* __restrict__ b_ih,
                                             const float* __restrict__ W_hh,
                                             const float* __restrict__ b_hh,
                                             float* __restrict__ out, int stage) {
  int wid = blockIdx.x * 4 + (threadIdx.x >> 6);
  int lane = threadIdx.x & 63;
  int b = wid >> 9, i = wid & 511;
  const float4* xz = (const float4*)(z + (size_t)b * cDU);
  const float4* xm = (const float4*)(memin + (size_t)b * cDM);
  float4 z0 = xz[lane * 2], z1 = xz[lane * 2 + 1];
  float4 m0 = xm[lane * 2], m1 = xm[lane * 2 + 1];
  float ysc = scal[b * 8 + 0];
  float sv = (lane < 32) ? sprp[b * 32 + lane] : 0.f;
  float spr_raw = wave_sum(sv);
  float aI[3], aH[3];
#pragma unroll
  for (int g = 0; g < 3; ++g) {
    size_t row = (size_t)(g * 512 + i);
    const float4* wI = (const float4*)(W_ih + row * 516);
    float a = dot4(z0, wI[lane * 2]) + dot4(z1, wI[lane * 2 + 1]);
    if (lane == 0) {
      float4 wt = wI[128];
      float cov = scal[b * 8 + 1], ent = scal[b * 8 + 2];
      float spr = spr_raw / ysc;
      float cmp = 2.f * (ysc * scal[b * 8 + 3] - scal[b * 8 + 6]) / fmaxf(ysc * ysc, cEPS);
      a += cov * wt.x + ent * wt.y + spr * wt.z + cmp * wt.w;
    }
    aI[g] = wave_sum(a);
    const float4* wH = (const float4*)(W_hh + row * cDM);
    float h = dot4(m0, wH[lane * 2]) + dot4(m1, wH[lane * 2 + 1]);
    aH[g] = wave_sum(h);
  }
  if (lane == 0) {
    float gir = aI[0] + b_ih[i],        ghr = aH[0] + b_hh[i];
    float giz = aI[1] + b_ih[512 + i],  ghz = aH[1] + b_hh[512 + i];
    float gin = aI[2] + b_ih[1024 + i], ghn = aH[2] + b_hh[1024 + i];
    float rg = 1.f / (1.f + expf(-(gir + ghr)));
    float zg = 1.f / (1.f + expf(-(giz + ghz)));
    float ng = tanhf(gin + rg * ghn);
    float mold = memin[b * cDM + i];
    memout[b * cDM + i] = (1.f - zg) * ng + zg * mold;
    out[(size_t)(b * cL + stage) * cDU + i] = z[b * cDU + i];
  }
}

extern "C" void kernel_launch(void* const* d_in, const int* in_sizes, int n_in,
                              void* d_out, int out_size, void* d_ws, size_t ws_size,
                              hipStream_t stream) {
  const float* u    = (const float*)d_in[0];
  const float* sf   = (const float*)d_in[1];
  const float* sim  = (const float*)d_in[2];
  const float* mem0 = (const float*)d_in[3];
  const float* Wq   = (const float*)d_in[4];
  const float* Wk   = (const float*)d_in[5];
  const float* Wv   = (const float*)d_in[6];
  const float* sbw1 = (const float*)d_in[7];
  const float* sbb1 = (const float*)d_in[8];
  const float* sbw2 = (const float*)d_in[9];
  const float* sbb2 = (const float*)d_in[10];
  const float* logt = (const float*)d_in[11];
  const float* W_ih = (const float*)d_in[12];
  const float* b_ih = (const float*)d_in[13];
  const float* W_hh = (const float*)d_in[14];
  const float* b_hh = (const float*)d_in[15];
  float* out = (float*)d_out;
  float* ws  = (float*)d_ws;
  u16* ubf  = (u16*)((char*)d_ws + U_OFFB);
  u8* sim8  = (u8*)((char*)d_ws + S8_OFFB);

  const int use_ubf = (ws_size >= WS_NEED_U) ? 1 : 0;
  const int use_s8  = (ws_size >= WS_NEED_ALL) ? 1 : 0;

  k_init<<<1024, 256, 0, stream>>>(u, sf, mem0, sbw1, sbb1, sbw2, sbb2,
                                   ws, ubf, use_ubf);

  for (int stage = 0; stage < cL; ++stage) {
    float* mcur = ws + ((stage & 1) ? F_M1 : F_M0);
    float* mnxt = ws + ((stage & 1) ? F_M0 : F_M1);
    k_qqk<<<cB, 1024, 0, stream>>>(mcur, Wq, Wk, ws + F_QK, ws + F_C);
    k_scores<<<4096, 256, 0, stream>>>(ubf, u, ws + F_QK, ws + F_SB, sim8, sim,
                                       ws + F_PR, logt, stage == 0 ? 0.0f : cGAMMA,
                                       use_ubf, use_s8, ws + F_LG);
    k_overlap<<<4096, 256, 0, stream>>>(sim8, sim8, sim, ws + F_LG, use_s8,
                                        (stage == 0 && use_s8) ? 1 : 0, ws + F_OV);
    k_statcen<<<dim3(32, cB), 256, 0, stream>>>(ws + F_OV, ws + F_LG, ws + F_UN,
                                                ubf, u, use_ubf,
                                                ws + F_Y, ws + F_PR, ws + F_SC, ws + F_C,
                                                stage == 0 ? 1 : 0);
    k_zyd<<<1280, 256, 0, stream>>>(ws + F_C, Wv, ubf, u, use_ubf,
                                    ws + F_UN, ws + F_Y, ws + F_Z, ws + F_SC, ws + F_SP);
    k_gru<<<1024, 256, 0, stream>>>(ws + F_Z, ws + F_SC, ws + F_SP, mcur, mnxt,
                                    W_ih, b_ih, W_hh, b_hh, out, stage);
  }
}

// Round 7
// 502.271 us; speedup vs baseline: 3.5185x; 1.1316x over previous
//
#include <hip/hip_runtime.h>
#include <math.h>

constexpr int cB = 8, cT = 2048, cDU = 512, cDM = 512, cDA = 256, cDF = 12, cL = 4;
constexpr float cEPS = 1e-6f;
constexpr float cSCALE = 16.0f;   // sqrt(DA)
constexpr float cGAMMA = 1.0f;

typedef unsigned short u16;
typedef unsigned char u8;
typedef u16 u16x8 __attribute__((ext_vector_type(8)));

// ---------------- workspace layout (float offsets) ----------------
constexpr size_t F_SB = 0;                 // sbias  B*T
constexpr size_t F_UN = F_SB + 16384;      // unorm2 B*T
constexpr size_t F_LG = F_UN + 16384;      // logits B*T
constexpr size_t F_Y  = F_LG + 16384;      // y (final, per stage) B*T
constexpr size_t F_PR = F_Y  + 16384;      // prev   B*T
constexpr size_t F_OV = F_PR + 16384;      // overlap B*T
constexpr size_t F_SP = F_OV + 16384;      // spread partials B*32
constexpr size_t F_QK = F_SP + 256;        // qk  B*DU
constexpr size_t F_M0 = F_QK + 4096;       // memory buf 0
constexpr size_t F_M1 = F_M0 + 4096;       // memory buf 1
constexpr size_t F_C  = F_M1 + 4096;       // c_raw B*DU
constexpr size_t F_Z  = F_C  + 4096;       // z B*DU
constexpr size_t F_SC = F_Z  + 4096;       // scalars B*8
constexpr size_t F_A  = F_SC + 64;         // A = Wk^T @ Wq, 512x512
constexpr size_t F_END = F_A + 262144;
constexpr size_t U_OFFB   = F_END * 4;                       // bf16 u
constexpr size_t U_BYTES  = (size_t)cB * cT * cDU * 2;
constexpr size_t S8_OFFB  = U_OFFB + U_BYTES;                // u8 sim
constexpr size_t S8_BYTES = (size_t)cB * cT * cT;
constexpr size_t WS_NEED_U   = S8_OFFB;
constexpr size_t WS_NEED_ALL = S8_OFFB + S8_BYTES;
// scal: 0 ysum_clamped, 1 coverage, 2 entropy, 3 wsq, 6 csq

__device__ __forceinline__ float wave_sum(float v) {
#pragma unroll
  for (int o = 32; o; o >>= 1) v += __shfl_down(v, o);
  return v;   // valid on lane 0
}
__device__ __forceinline__ u16 f2bf(float f) {
  unsigned u = __float_as_uint(f);
  return (u16)((u + 0x7fffu + ((u >> 16) & 1u)) >> 16);
}
__device__ __forceinline__ float bf2f(u16 h) { return __uint_as_float(((unsigned)h) << 16); }
__device__ __forceinline__ float dot4(float4 a, float4 b) {
  return a.x * b.x + a.y * b.y + a.z * b.z + a.w * b.w;
}
__device__ __forceinline__ unsigned pack4(float a, float b, float c, float d) {
  unsigned b0 = (unsigned)(a * 255.f + 0.5f);
  unsigned b1 = (unsigned)(b * 255.f + 0.5f);
  unsigned b2 = (unsigned)(c * 255.f + 0.5f);
  unsigned b3 = (unsigned)(d * 255.f + 0.5f);
  return b0 | (b1 << 8) | (b2 << 16) | (b3 << 24);
}
__device__ __forceinline__ void dotu8(float& sd, unsigned w, float4 p) {
  sd += (float)(w & 255u) * p.x + (float)((w >> 8) & 255u) * p.y +
        (float)((w >> 16) & 255u) * p.z + (float)(w >> 24) * p.w;
}

// ==== k_init: blocks 0..1023 mem0 copy + u->bf16 + sbias/unorm2; 1024..1087 A=Wk^T@Wq ==
__global__ __launch_bounds__(256) void k_init(
    const float* __restrict__ u, const float* __restrict__ sf,
    const float* __restrict__ mem0,
    const float* __restrict__ Wq, const float* __restrict__ Wk,
    const float* __restrict__ w1, const float* __restrict__ b1,
    const float* __restrict__ w2, const float* __restrict__ b2,
    float* __restrict__ wsf, u16* __restrict__ ubf, int use_ubf) {
  const int tid = threadIdx.x;
  if (blockIdx.x >= 1024) {
    // A[j,i] = sum_a Wk[a,j] * Wq[a,i];  block handles 8 j rows
    __shared__ float wkj[32][8];
    int j0 = (blockIdx.x - 1024) * 8;
    float acc[8][2] = {};
    for (int a0 = 0; a0 < cDA; a0 += 32) {
      wkj[tid >> 3][tid & 7] = Wk[(size_t)(a0 + (tid >> 3)) * cDU + j0 + (tid & 7)];
      __syncthreads();
#pragma unroll 8
      for (int aa = 0; aa < 32; ++aa) {
        float wq0 = Wq[(size_t)(a0 + aa) * cDM + tid * 2];
        float wq1 = Wq[(size_t)(a0 + aa) * cDM + tid * 2 + 1];
#pragma unroll
        for (int r = 0; r < 8; ++r) {
          acc[r][0] += wkj[aa][r] * wq0;
          acc[r][1] += wkj[aa][r] * wq1;
        }
      }
      __syncthreads();
    }
#pragma unroll
    for (int r = 0; r < 8; ++r) {
      wsf[F_A + (size_t)(j0 + r) * cDU + tid * 2] = acc[r][0];
      wsf[F_A + (size_t)(j0 + r) * cDU + tid * 2 + 1] = acc[r][1];
    }
    return;
  }
  const int gt = blockIdx.x * 256 + tid;
  const int nt = 1024 * 256;
  const int wv = tid >> 6, lane = tid & 63;
  const int gw = blockIdx.x * 4 + wv;
  const int nw = 1024 * 4;

  for (int i = gt; i < cB * cDM; i += nt) wsf[F_M0 + i] = mem0[i];

  if (use_ubf) {
    const int NU8 = cB * cT * cDU / 8;
    const float4* src = (const float4*)u;
    for (int c = gt; c < NU8; c += nt) {
      float4 f0 = src[(size_t)c * 2], f1 = src[(size_t)c * 2 + 1];
      u16x8 o;
      o[0] = f2bf(f0.x); o[1] = f2bf(f0.y); o[2] = f2bf(f0.z); o[3] = f2bf(f0.w);
      o[4] = f2bf(f1.x); o[5] = f2bf(f1.y); o[6] = f2bf(f1.z); o[7] = f2bf(f1.w);
      *(u16x8*)(ubf + (size_t)c * 8) = o;
    }
  }
  for (int row = gw; row < cB * cT; row += nw) {
    float d0 = sf[(size_t)row * cDF + 8];
    float d1 = sf[(size_t)row * cDF + 9];
    float d2 = sf[(size_t)row * cDF + 10];
    float acc = 0.f;
#pragma unroll
    for (int i = 0; i < 4; ++i) {
      int a = lane * 4 + i;
      float h = d0 * w1[a * 3 + 0] + d1 * w1[a * 3 + 1] + d2 * w1[a * 3 + 2] + b1[a];
      float g = 0.5f * h * (1.0f + erff(h * 0.70710678118654752f));
      acc += g * w2[a];
    }
    float un = 0.f;
    const float4* ur = (const float4*)(u + (size_t)row * cDU);
#pragma unroll
    for (int m = 0; m < 2; ++m) { float4 x = ur[lane + m * 64]; un += dot4(x, x); }
    acc = wave_sum(acc);
    un = wave_sum(un);
    if (lane == 0) { wsf[F_SB + row] = acc + b2[0]; wsf[F_UN + row] = un; }
  }
}

// =============== k_qk: qk[b,:] = A @ mem[b,:] (wave per (b,j)); zero c_raw ===========
__global__ __launch_bounds__(256) void k_qk(const float* __restrict__ A,
                                            const float* __restrict__ mem,
                                            float* __restrict__ qk,
                                            float* __restrict__ c_raw) {
  int wv = threadIdx.x >> 6, lane = threadIdx.x & 63;
  int wid = blockIdx.x * 4 + wv;             // 0..4095
  int b = wid >> 9, j = wid & 511;
  const float4* ar = (const float4*)(A + (size_t)j * cDM);
  const float4* mr = (const float4*)(mem + (size_t)b * cDM);
  float acc = dot4(ar[lane * 2], mr[lane * 2]) + dot4(ar[lane * 2 + 1], mr[lane * 2 + 1]);
  acc = wave_sum(acc);
  if (lane == 0) qk[b * cDU + j] = acc;
  int gt = blockIdx.x * 256 + threadIdx.x;
  if (gt < cB * cDU) c_raw[gt] = 0.f;
}

// =============== k_scores: logits = (u.qk/SCALE + sbias - g*sim@prev)/temp ===========
__global__ __launch_bounds__(256) void k_scores(
    const u16* __restrict__ ubf, const float* __restrict__ uf,
    const float* __restrict__ qk, const float* __restrict__ sbias,
    const u8* __restrict__ sim8, const float* __restrict__ simf,
    const float* __restrict__ prev, const float* __restrict__ log_temp,
    float gamma, int use_ubf, int use_s8, float* __restrict__ logits) {
  int wid = (blockIdx.x * blockDim.x + threadIdx.x) >> 6;
  int lane = threadIdx.x & 63;
  int b = wid >> 11;
  const float4* qk4 = (const float4*)(qk + (size_t)b * cDU);
  float4 q0 = qk4[lane * 2], q1 = qk4[lane * 2 + 1];
  float acc;
  if (use_ubf) {
    u16x8 s = *(const u16x8*)(ubf + (size_t)wid * cDU + lane * 8);
    acc = bf2f(s[0]) * q0.x + bf2f(s[1]) * q0.y + bf2f(s[2]) * q0.z + bf2f(s[3]) * q0.w +
          bf2f(s[4]) * q1.x + bf2f(s[5]) * q1.y + bf2f(s[6]) * q1.z + bf2f(s[7]) * q1.w;
  } else {
    const float4* ur = (const float4*)(uf + (size_t)wid * cDU);
    acc = dot4(ur[lane * 2], q0) + dot4(ur[lane * 2 + 1], q1);
  }
  acc *= (1.0f / cSCALE);
  if (gamma != 0.0f) {
    float sd = 0.f;
    const float4* pr4 = (const float4*)(prev + (size_t)b * cT);
    if (use_s8) {
#pragma unroll
      for (int m = 0; m < 2; ++m) {
        uint4 sq = *(const uint4*)(sim8 + (size_t)wid * cT + m * 1024 + lane * 16);
        const float4* pb = pr4 + m * 256 + lane * 4;
        dotu8(sd, sq.x, pb[0]); dotu8(sd, sq.y, pb[1]);
        dotu8(sd, sq.z, pb[2]); dotu8(sd, sq.w, pb[3]);
      }
      sd *= (1.0f / 255.0f);
    } else {
      const float4* sr = (const float4*)(simf + (size_t)wid * cT);
#pragma unroll
      for (int m = 0; m < 8; ++m) sd += dot4(sr[lane + m * 64], pr4[lane + m * 64]);
    }
    acc -= gamma * sd;
  }
  acc = wave_sum(acc);
  if (lane == 0) {
    float temp = fminf(fmaxf(expf(log_temp[0]), 0.1f), 10.0f);
    logits[wid] = (acc + sbias[wid]) / temp;
  }
}

// =============== k_overlap: softmax(logits) once per 16 rows + overlap = sim @ y1 =====
// grid 1024, block 256; block handles 16 rows (4 per wave). convert: also emit u8 sim.
__global__ __launch_bounds__(256) void k_overlap(
    const u8* __restrict__ sim8c, u8* __restrict__ sim8w,
    const float* __restrict__ simf,
    const float* __restrict__ logits, int use_s8, int convert,
    float* __restrict__ overlap) {
  __shared__ float ylds[2176];   // padded: a = s + (s>>4)
  __shared__ float red[256];
  const int tid = threadIdx.x;
  const int wv = tid >> 6, lane = tid & 63;
  const int b = blockIdx.x >> 7;               // 128 blocks per b
  float l[8];
  float mx = -INFINITY;
#pragma unroll
  for (int e = 0; e < 8; ++e) { l[e] = logits[b * cT + e * 256 + tid]; mx = fmaxf(mx, l[e]); }
  red[tid] = mx; __syncthreads();
  for (int s2 = 128; s2; s2 >>= 1) { if (tid < s2) red[tid] = fmaxf(red[tid], red[tid + s2]); __syncthreads(); }
  mx = red[0]; __syncthreads();
  float sum = 0.f;
#pragma unroll
  for (int e = 0; e < 8; ++e) {
    float ev = expf(l[e] - mx);
    sum += ev;
    int s = e * 256 + tid;
    ylds[s + (s >> 4)] = ev;
  }
  red[tid] = sum; __syncthreads();
  for (int s2 = 128; s2; s2 >>= 1) { if (tid < s2) red[tid] += red[tid + s2]; __syncthreads(); }
  float invS = 1.f / red[0];
  __syncthreads();
  for (int r = 0; r < 4; ++r) {
    int row = blockIdx.x * 16 + wv * 4 + r;
    float acc = 0.f;
    if (use_s8 && !convert) {
#pragma unroll
      for (int m = 0; m < 2; ++m) {
        uint4 sq = *(const uint4*)(sim8c + (size_t)row * cT + m * 1024 + lane * 16);
        int s0 = m * 1024 + lane * 16;
#pragma unroll
        for (int k = 0; k < 4; ++k) {
          unsigned w = (&sq.x)[k];
          int s = s0 + k * 4;
          acc += (float)(w & 255u)         * ylds[s + (s >> 4)] +
                 (float)((w >> 8) & 255u)  * ylds[(s + 1) + ((s + 1) >> 4)] +
                 (float)((w >> 16) & 255u) * ylds[(s + 2) + ((s + 2) >> 4)] +
                 (float)(w >> 24)          * ylds[(s + 3) + ((s + 3) >> 4)];
        }
      }
      acc *= (1.0f / 255.0f);
    } else {
#pragma unroll
      for (int m = 0; m < 2; ++m) {
        const float4* sr = (const float4*)(simf + (size_t)row * cT + m * 1024 + lane * 16);
        uint4 oq;
#pragma unroll
        for (int k = 0; k < 4; ++k) {
          float4 sv = sr[k];
          int s = m * 1024 + lane * 16 + k * 4;
          acc += sv.x * ylds[s + (s >> 4)] + sv.y * ylds[(s + 1) + ((s + 1) >> 4)] +
                 sv.z * ylds[(s + 2) + ((s + 2) >> 4)] + sv.w * ylds[(s + 3) + ((s + 3) >> 4)];
          (&oq.x)[k] = pack4(sv.x, sv.y, sv.z, sv.w);
        }
        if (convert)
          *(uint4*)(sim8w + (size_t)row * cT + m * 1024 + lane * 16) = oq;
      }
    }
    acc = wave_sum(acc);
    if (lane == 0) overlap[row] = acc * invS;
  }
}

// =============== k_statcen: penalty+resoftmax+stats + centroid chunk accum ===========
__global__ __launch_bounds__(256) void k_statcen(
    const float* __restrict__ overlap, const float* __restrict__ logits,
    const float* __restrict__ unorm2,
    const u16* __restrict__ ubf, const float* __restrict__ uf, int use_ubf,
    float* __restrict__ y, float* __restrict__ prev,
    float* __restrict__ scal, float* __restrict__ c_raw, int first_stage) {
  __shared__ float ylds[2048];
  __shared__ float comb[2048];
  __shared__ float red[256];
  const int tid = threadIdx.x;
  const int wv = tid >> 6, lane = tid & 63;
  const int ch = blockIdx.x, b = blockIdx.y;
  float o[8], l[8], yv[8];
  float mo = -INFINITY;
#pragma unroll
  for (int e = 0; e < 8; ++e) { o[e] = overlap[b * cT + e * 256 + tid]; mo = fmaxf(mo, o[e]); }
  red[tid] = mo; __syncthreads();
  for (int s2 = 128; s2; s2 >>= 1) { if (tid < s2) red[tid] = fmaxf(red[tid], red[tid + s2]); __syncthreads(); }
  mo = fmaxf(red[0], cEPS); __syncthreads();
  float ml = -INFINITY;
#pragma unroll
  for (int e = 0; e < 8; ++e) { l[e] = logits[b * cT + e * 256 + tid] - o[e] / mo; ml = fmaxf(ml, l[e]); }
  red[tid] = ml; __syncthreads();
  for (int s2 = 128; s2; s2 >>= 1) { if (tid < s2) red[tid] = fmaxf(red[tid], red[tid + s2]); __syncthreads(); }
  ml = red[0]; __syncthreads();
  float sum = 0.f;
#pragma unroll
  for (int e = 0; e < 8; ++e) { l[e] = expf(l[e] - ml); sum += l[e]; }
  red[tid] = sum; __syncthreads();
  for (int s2 = 128; s2; s2 >>= 1) { if (tid < s2) red[tid] += red[tid + s2]; __syncthreads(); }
  float inv = 1.f / red[0]; __syncthreads();
  float ysr_p = 0.f, wsq_p = 0.f;
#pragma unroll
  for (int e = 0; e < 8; ++e) {
    yv[e] = l[e] * inv;
    ylds[e * 256 + tid] = yv[e];
    ysr_p += yv[e];
    wsq_p += yv[e] * unorm2[b * cT + e * 256 + tid];
  }
  red[tid] = ysr_p; __syncthreads();
  for (int s2 = 128; s2; s2 >>= 1) { if (tid < s2) red[tid] += red[tid + s2]; __syncthreads(); }
  float ysr = red[0]; __syncthreads();
  float ysc = fmaxf(ysr, cEPS);
  red[tid] = wsq_p; __syncthreads();
  for (int s2 = 128; s2; s2 >>= 1) { if (tid < s2) red[tid] += red[tid + s2]; __syncthreads(); }
  float wsq = red[0]; __syncthreads();
  float ent_p = 0.f;
#pragma unroll
  for (int e = 0; e < 8; ++e) {
    float yn = yv[e] / ysc;
    ent_p -= yn * logf(fmaxf(yn, cEPS));
  }
  red[tid] = ent_p; __syncthreads();
  for (int s2 = 128; s2; s2 >>= 1) { if (tid < s2) red[tid] += red[tid + s2]; __syncthreads(); }
  float ent = red[0]; __syncthreads();
  if (ch == 0) {
#pragma unroll
    for (int e = 0; e < 8; ++e) {
      int idx = b * cT + e * 256 + tid;
      y[idx] = yv[e];
      if (first_stage) prev[idx] = yv[e]; else prev[idx] += yv[e];
    }
    if (tid == 0) {
      scal[b * 8 + 0] = ysc;
      scal[b * 8 + 1] = ysr / (float)cT;
      scal[b * 8 + 2] = ent;
      scal[b * 8 + 3] = wsq;
    }
  }
  float acc[8] = {};
  for (int i = 0; i < 16; ++i) {
    int r = ch * 64 + wv * 16 + i;
    float yvv = ylds[r];
    int row = b * cT + r;
    if (use_ubf) {
      u16x8 s8 = *(const u16x8*)(ubf + (size_t)row * cDU + lane * 8);
#pragma unroll
      for (int e = 0; e < 8; ++e) acc[e] += yvv * bf2f(s8[e]);
    } else {
      const float4* ur = (const float4*)(uf + (size_t)row * cDU);
      float4 a0 = ur[lane * 2], a1 = ur[lane * 2 + 1];
      acc[0] += yvv * a0.x; acc[1] += yvv * a0.y; acc[2] += yvv * a0.z; acc[3] += yvv * a0.w;
      acc[4] += yvv * a1.x; acc[5] += yvv * a1.y; acc[6] += yvv * a1.z; acc[7] += yvv * a1.w;
    }
  }
  __syncthreads();
#pragma unroll
  for (int e = 0; e < 8; ++e) comb[wv * 512 + lane * 8 + e] = acc[e];
  __syncthreads();
  float s0 = comb[tid] + comb[512 + tid] + comb[1024 + tid] + comb[1536 + tid];
  float s1 = comb[tid + 256] + comb[512 + tid + 256] + comb[1024 + tid + 256] + comb[1536 + tid + 256];
  atomicAdd(&c_raw[b * cDU + tid], s0);
  atomicAdd(&c_raw[b * cDU + tid + 256], s1);
}

// =============== k_zyd: blocks 0..1023 -> z = c_raw@Wv^T ; 1024..1279 -> spread ======
__global__ __launch_bounds__(256) void k_zyd(
    const float* __restrict__ c_raw, const float* __restrict__ Wv,
    const u16* __restrict__ ubf, const float* __restrict__ uf, int use_ubf,
    const float* __restrict__ unorm2, const float* __restrict__ y,
    float* __restrict__ z, float* __restrict__ scal, float* __restrict__ sprp) {
  __shared__ float s4[4];
  int wv = threadIdx.x >> 6, lane = threadIdx.x & 63;
  if (blockIdx.x < 1024) {
    int wid = blockIdx.x * 4 + wv;
    int b = wid >> 9, j = wid & 511;
    const float4* c4 = (const float4*)(c_raw + (size_t)b * cDU);
    const float4* w4 = (const float4*)(Wv + (size_t)j * cDU);
    float acc = dot4(c4[lane * 2], w4[lane * 2]) + dot4(c4[lane * 2 + 1], w4[lane * 2 + 1]);
    acc = wave_sum(acc);
    if (lane == 0) z[b * cDU + j] = acc;
    return;
  }
  int unit = blockIdx.x - 1024;   // 0..255
  int b = unit >> 5, tc = unit & 31;
  float ysc = scal[b * 8 + 0];
  float inv = 1.f / ysc;
  const float4* c4 = (const float4*)(c_raw + (size_t)b * cDU);
  float4 cr0 = c4[lane * 2], cr1 = c4[lane * 2 + 1];
  float4 cx0, cx1;
  cx0.x = cr0.x * inv; cx0.y = cr0.y * inv; cx0.z = cr0.z * inv; cx0.w = cr0.w * inv;
  cx1.x = cr1.x * inv; cx1.y = cr1.y * inv; cx1.z = cr1.z * inv; cx1.w = cr1.w * inv;
  float cen2 = wave_sum(dot4(cx0, cx0) + dot4(cx1, cx1));     // lane0-valid
  if (tc == 0 && wv == 0) {
    float csq = wave_sum(dot4(cr0, cr0) + dot4(cr1, cr1));
    if (lane == 0) scal[b * 8 + 6] = csq;
  }
  float part = 0.f;
  for (int i = 0; i < 16; ++i) {
    int row = b * cT + tc * 64 + wv * 16 + i;
    float dot;
    if (use_ubf) {
      u16x8 s = *(const u16x8*)(ubf + (size_t)row * cDU + lane * 8);
      dot = bf2f(s[0]) * cx0.x + bf2f(s[1]) * cx0.y + bf2f(s[2]) * cx0.z + bf2f(s[3]) * cx0.w +
            bf2f(s[4]) * cx1.x + bf2f(s[5]) * cx1.y + bf2f(s[6]) * cx1.z + bf2f(s[7]) * cx1.w;
    } else {
      const float4* ur = (const float4*)(uf + (size_t)row * cDU);
      dot = dot4(ur[lane * 2], cx0) + dot4(ur[lane * 2 + 1], cx1);
    }
    dot = wave_sum(dot);
    if (lane == 0) {
      float d2 = unorm2[row] - 2.f * dot + cen2;
      part += y[row] * sqrtf(fmaxf(d2, 0.f));
    }
  }
  if (lane == 0) s4[wv] = part;
  __syncthreads();
  if (threadIdx.x == 0) sprp[b * 32 + tc] = s4[0] + s4[1] + s4[2] + s4[3];
}

// =============== k_gru: gates + memory update + output (wave per (b,i)) ==============
__global__ __launch_bounds__(256) void k_gru(const float* __restrict__ z,
                                             const float* __restrict__ scal,
                                             const float* __restrict__ sprp,
                                             const float* __restrict__ memin,
                                             float* __restrict__ memout,
                                             const float* __restrict__ W_ih,
                                             const float* __restrict__ b_ih,
                                             const float* __restrict__ W_hh,
                                             const float* __restrict__ b_hh,
                                             float* __restrict__ out, int stage) {
  int wid = blockIdx.x * 4 + (threadIdx.x >> 6);
  int lane = threadIdx.x & 63;
  int b = wid >> 9, i = wid & 511;
  const float4* xz = (const float4*)(z + (size_t)b * cDU);
  const float4* xm = (const float4*)(memin + (size_t)b * cDM);
  float4 z0 = xz[lane * 2], z1 = xz[lane * 2 + 1];
  float4 m0 = xm[lane * 2], m1 = xm[lane * 2 + 1];
  float ysc = scal[b * 8 + 0];
  float sv = (lane < 32) ? sprp[b * 32 + lane] : 0.f;
  float spr_raw = wave_sum(sv);
  float aI[3], aH[3];
#pragma unroll
  for (int g = 0; g < 3; ++g) {
    size_t row = (size_t)(g * 512 + i);
    const float4* wI = (const float4*)(W_ih + row * 516);
    float a = dot4(z0, wI[lane * 2]) + dot4(z1, wI[lane * 2 + 1]);
    if (lane == 0) {
      float4 wt = wI[128];
      float cov = scal[b * 8 + 1], ent = scal[b * 8 + 2];
      float spr = spr_raw / ysc;
      float cmp = 2.f * (ysc * scal[b * 8 + 3] - scal[b * 8 + 6]) / fmaxf(ysc * ysc, cEPS);
      a += cov * wt.x + ent * wt.y + spr * wt.z + cmp * wt.w;
    }
    aI[g] = wave_sum(a);
    const float4* wH = (const float4*)(W_hh + row * cDM);
    float h = dot4(m0, wH[lane * 2]) + dot4(m1, wH[lane * 2 + 1]);
    aH[g] = wave_sum(h);
  }
  if (lane == 0) {
    float gir = aI[0] + b_ih[i],        ghr = aH[0] + b_hh[i];
    float giz = aI[1] + b_ih[512 + i],  ghz = aH[1] + b_hh[512 + i];
    float gin = aI[2] + b_ih[1024 + i], ghn = aH[2] + b_hh[1024 + i];
    float rg = 1.f / (1.f + expf(-(gir + ghr)));
    float zg = 1.f / (1.f + expf(-(giz + ghz)));
    float ng = tanhf(gin + rg * ghn);
    float mold = memin[b * cDM + i];
    memout[b * cDM + i] = (1.f - zg) * ng + zg * mold;
    out[(size_t)(b * cL + stage) * cDU + i] = z[b * cDU + i];
  }
}

extern "C" void kernel_launch(void* const* d_in, const int* in_sizes, int n_in,
                              void* d_out, int out_size, void* d_ws, size_t ws_size,
                              hipStream_t stream) {
  const float* u    = (const float*)d_in[0];
  const float* sf   = (const float*)d_in[1];
  const float* sim  = (const float*)d_in[2];
  const float* mem0 = (const float*)d_in[3];
  const float* Wq   = (const float*)d_in[4];
  const float* Wk   = (const float*)d_in[5];
  const float* Wv   = (const float*)d_in[6];
  const float* sbw1 = (const float*)d_in[7];
  const float* sbb1 = (const float*)d_in[8];
  const float* sbw2 = (const float*)d_in[9];
  const float* sbb2 = (const float*)d_in[10];
  const float* logt = (const float*)d_in[11];
  const float* W_ih = (const float*)d_in[12];
  const float* b_ih = (const float*)d_in[13];
  const float* W_hh = (const float*)d_in[14];
  const float* b_hh = (const float*)d_in[15];
  float* out = (float*)d_out;
  float* ws  = (float*)d_ws;
  u16* ubf  = (u16*)((char*)d_ws + U_OFFB);
  u8* sim8  = (u8*)((char*)d_ws + S8_OFFB);

  const int use_ubf = (ws_size >= WS_NEED_U) ? 1 : 0;
  const int use_s8  = (ws_size >= WS_NEED_ALL) ? 1 : 0;

  k_init<<<1088, 256, 0, stream>>>(u, sf, mem0, Wq, Wk, sbw1, sbb1, sbw2, sbb2,
                                   ws, ubf, use_ubf);

  for (int stage = 0; stage < cL; ++stage) {
    float* mcur = ws + ((stage & 1) ? F_M1 : F_M0);
    float* mnxt = ws + ((stage & 1) ? F_M0 : F_M1);
    k_qk<<<1024, 256, 0, stream>>>(ws + F_A, mcur, ws + F_QK, ws + F_C);
    k_scores<<<4096, 256, 0, stream>>>(ubf, u, ws + F_QK, ws + F_SB, sim8, sim,
                                       ws + F_PR, logt, stage == 0 ? 0.0f : cGAMMA,
                                       use_ubf, use_s8, ws + F_LG);
    k_overlap<<<1024, 256, 0, stream>>>(sim8, sim8, sim, ws + F_LG, use_s8,
                                        (stage == 0 && use_s8) ? 1 : 0, ws + F_OV);
    k_statcen<<<dim3(32, cB), 256, 0, stream>>>(ws + F_OV, ws + F_LG, ws + F_UN,
                                                ubf, u, use_ubf,
                                                ws + F_Y, ws + F_PR, ws + F_SC, ws + F_C,
                                                stage == 0 ? 1 : 0);
    k_zyd<<<1280, 256, 0, stream>>>(ws + F_C, Wv, ubf, u, use_ubf,
                                    ws + F_UN, ws + F_Y, ws + F_Z, ws + F_SC, ws + F_SP);
    k_gru<<<1024, 256, 0, stream>>>(ws + F_Z, ws + F_SC, ws + F_SP, mcur, mnxt,
                                    W_ih, b_ih, W_hh, b_hh, out, stage);
  }
}